// Round 1
// baseline (2243.196 us; speedup 1.0000x reference)
//
#include <hip/hip_runtime.h>
#include <math.h>

#define DIM 1024
#define SEQ 1024
#define BATCH 4
#define NHEADS 16
#define HEADD 64
#define MLP_DIM 4096

// ---------------- LayerNorm: one block per row (rows = 4096) ----------------
__global__ __launch_bounds__(256) void ln_kernel(const float* __restrict__ x,
                                                 const float* __restrict__ g,
                                                 const float* __restrict__ b,
                                                 float* __restrict__ out) {
  int row = blockIdx.x;
  int t = threadIdx.x;
  const float* xr = x + (size_t)row * DIM;
  float4 v = *(const float4*)(xr + t * 4);
  float s  = v.x + v.y + v.z + v.w;
  float sq = v.x * v.x + v.y * v.y + v.z * v.z + v.w * v.w;
#pragma unroll
  for (int off = 32; off > 0; off >>= 1) {
    s  += __shfl_down(s, off);
    sq += __shfl_down(sq, off);
  }
  __shared__ float red_s[4], red_q[4];
  __shared__ float mu_s, inv_s;
  int wid = t >> 6;
  if ((t & 63) == 0) { red_s[wid] = s; red_q[wid] = sq; }
  __syncthreads();
  if (t == 0) {
    float S  = red_s[0] + red_s[1] + red_s[2] + red_s[3];
    float Sq = red_q[0] + red_q[1] + red_q[2] + red_q[3];
    float mu  = S * (1.0f / DIM);
    float var = Sq * (1.0f / DIM) - mu * mu;
    mu_s  = mu;
    inv_s = 1.0f / sqrtf(var + 1e-5f);
  }
  __syncthreads();
  float mu = mu_s, inv = inv_s;
  float4 gv = *(const float4*)(g + t * 4);
  float4 bv = *(const float4*)(b + t * 4);
  float4 o;
  o.x = (v.x - mu) * inv * gv.x + bv.x;
  o.y = (v.y - mu) * inv * gv.y + bv.y;
  o.z = (v.z - mu) * inv * gv.z + bv.z;
  o.w = (v.w - mu) * inv * gv.w + bv.w;
  *(float4*)(out + (size_t)row * DIM + t * 4) = o;
}

// ---------------- fp32 SIMT GEMM: 128x128 tile, BK=16, 256 threads ----------
// C(MxN) = A(MxK) @ B(KxN)  [+ bias[col]] [gelu] [+ res[row*N+col]]
template <bool BIAS, bool RES, bool GELU>
__device__ __forceinline__ void gemm_body(const float* __restrict__ A,
                                          const float* __restrict__ B,
                                          const float* __restrict__ bias,
                                          const float* __restrict__ res,
                                          float* __restrict__ C,
                                          int M, int N, int K) {
  __shared__ float As[16][128];
  __shared__ float Bs[16][128];
  const int t  = threadIdx.x;
  const int tx = t & 15;   // N direction
  const int ty = t >> 4;   // M direction
  const int m0 = blockIdx.y * 128;
  const int n0 = blockIdx.x * 128;
  float acc[2][2][4][4] = {};
  const float* Aptr = A + (size_t)m0 * K;
  const float* Bptr = B + n0;

  for (int k0 = 0; k0 < K; k0 += 16) {
#pragma unroll
    for (int i = 0; i < 2; i++) {
      int f = t + i * 256;                 // 512 float4 of A tile
      int row = f >> 2, quad = f & 3;
      float4 va = *(const float4*)(Aptr + (size_t)row * K + k0 + quad * 4);
      As[quad * 4 + 0][row] = va.x;
      As[quad * 4 + 1][row] = va.y;
      As[quad * 4 + 2][row] = va.z;
      As[quad * 4 + 3][row] = va.w;
    }
#pragma unroll
    for (int i = 0; i < 2; i++) {
      int f = t + i * 256;                 // 512 float4 of B tile
      int row = f >> 5, c4 = (f & 31) * 4;
      *(float4*)&Bs[row][c4] = *(const float4*)(Bptr + (size_t)(k0 + row) * N + c4);
    }
    __syncthreads();
#pragma unroll
    for (int k = 0; k < 16; k++) {
      float4 a0 = *(const float4*)&As[k][ty * 4];
      float4 a1 = *(const float4*)&As[k][64 + ty * 4];
      float4 b0 = *(const float4*)&Bs[k][tx * 4];
      float4 b1 = *(const float4*)&Bs[k][64 + tx * 4];
      float av[2][4] = {{a0.x, a0.y, a0.z, a0.w}, {a1.x, a1.y, a1.z, a1.w}};
      float bv[2][4] = {{b0.x, b0.y, b0.z, b0.w}, {b1.x, b1.y, b1.z, b1.w}};
#pragma unroll
      for (int qr = 0; qr < 2; qr++)
#pragma unroll
        for (int r = 0; r < 4; r++)
#pragma unroll
          for (int qc = 0; qc < 2; qc++)
#pragma unroll
            for (int c = 0; c < 4; c++)
              acc[qr][qc][r][c] += av[qr][r] * bv[qc][c];
    }
    __syncthreads();
  }

#pragma unroll
  for (int qr = 0; qr < 2; qr++) {
#pragma unroll
    for (int r = 0; r < 4; r++) {
      int row = m0 + qr * 64 + ty * 4 + r;
#pragma unroll
      for (int qc = 0; qc < 2; qc++) {
        int col = n0 + qc * 64 + tx * 4;
        float4 v = make_float4(acc[qr][qc][r][0], acc[qr][qc][r][1],
                               acc[qr][qc][r][2], acc[qr][qc][r][3]);
        if (BIAS) {
          float4 bb = *(const float4*)(bias + col);
          v.x += bb.x; v.y += bb.y; v.z += bb.z; v.w += bb.w;
        }
        if (GELU) {
          v.x = 0.5f * v.x * (1.0f + erff(v.x * 0.70710678118654752f));
          v.y = 0.5f * v.y * (1.0f + erff(v.y * 0.70710678118654752f));
          v.z = 0.5f * v.z * (1.0f + erff(v.z * 0.70710678118654752f));
          v.w = 0.5f * v.w * (1.0f + erff(v.w * 0.70710678118654752f));
        }
        if (RES) {
          float4 rr = *(const float4*)(res + (size_t)row * N + col);
          v.x += rr.x; v.y += rr.y; v.z += rr.z; v.w += rr.w;
        }
        *(float4*)(C + (size_t)row * N + col) = v;
      }
    }
  }
}

template <bool BIAS, bool RES, bool GELU>
__global__ __launch_bounds__(256, 2) void gemm_kernel(const float* __restrict__ A,
                                                      const float* __restrict__ B,
                                                      const float* __restrict__ bias,
                                                      const float* __restrict__ res,
                                                      float* __restrict__ C,
                                                      int M, int N, int K) {
  gemm_body<BIAS, RES, GELU>(A, B, bias, res, C, M, N, K);
}

// fused QKV: blockIdx.z selects weight/output (one launch, 768 blocks)
__global__ __launch_bounds__(256, 2) void qkv_kernel(const float* __restrict__ A,
                                                     const float* __restrict__ Wq,
                                                     const float* __restrict__ Wk,
                                                     const float* __restrict__ Wv,
                                                     float* __restrict__ Qo,
                                                     float* __restrict__ Ko,
                                                     float* __restrict__ Vo) {
  const float* B = (blockIdx.z == 0) ? Wq : (blockIdx.z == 1) ? Wk : Wv;
  float* C = (blockIdx.z == 0) ? Qo : (blockIdx.z == 1) ? Ko : Vo;
  gemm_body<false, false, false>(A, B, nullptr, nullptr, C, 4096, DIM, DIM);
}

// ---------------- attention ----------------
// Per (batch b, head n): the "view" makes Qh = Qmat[b, n*64:(n+1)*64, :]
// (contiguous 64*1024 floats) reinterpreted as (1024, 64) row-major.
// scores = Qh @ Kh^T / 8 ; softmax ; O = P @ Vh ; Omat[b][li][n*64+hd] = O[li][hd].
// One thread per query row; K/V tiles of 128 rows staged in LDS.
__global__ __launch_bounds__(256, 2) void attn_kernel(const float* __restrict__ Q,
                                                      const float* __restrict__ K,
                                                      const float* __restrict__ V,
                                                      float* __restrict__ O) {
  const int qt = blockIdx.x;   // 0..3
  const int n  = blockIdx.y;   // 0..15
  const int bi = blockIdx.z;   // 0..3
  const size_t headoff = ((size_t)bi * SEQ + (size_t)n * HEADD) * DIM;
  const float* Qh = Q + headoff;
  const float* Kh = K + headoff;
  const float* Vh = V + headoff;
  const int t  = threadIdx.x;
  const int li = qt * 256 + t;

  float qv[64];
#pragma unroll
  for (int i = 0; i < 16; i++) {
    float4 v = *(const float4*)(Qh + (size_t)li * 64 + i * 4);
    qv[i * 4 + 0] = v.x; qv[i * 4 + 1] = v.y;
    qv[i * 4 + 2] = v.z; qv[i * 4 + 3] = v.w;
  }
  float acc[64] = {};
  float m = -1e30f, l = 0.0f;

  __shared__ float Ks[128 * 64];
  __shared__ float Vs[128 * 64];

  for (int kt = 0; kt < 8; kt++) {
    __syncthreads();   // previous tile fully consumed
    const float4* Ksrc = (const float4*)(Kh + (size_t)kt * 128 * 64);
    const float4* Vsrc = (const float4*)(Vh + (size_t)kt * 128 * 64);
    float4* Kdst = (float4*)Ks;
    float4* Vdst = (float4*)Vs;
#pragma unroll
    for (int i = 0; i < 8; i++) {
      Kdst[t + i * 256] = Ksrc[t + i * 256];
      Vdst[t + i * 256] = Vsrc[t + i * 256];
    }
    __syncthreads();

    for (int sub = 0; sub < 8; sub++) {
      float s[16];
      float subm = -1e30f;
#pragma unroll
      for (int jj = 0; jj < 16; jj++) {
        const float* kr = Ks + (sub * 16 + jj) * 64;
        float d0 = 0, d1 = 0, d2 = 0, d3 = 0;
#pragma unroll
        for (int i = 0; i < 4; i++) {
          float4 k0 = *(const float4*)(kr + i * 16 + 0);
          float4 k1 = *(const float4*)(kr + i * 16 + 4);
          float4 k2 = *(const float4*)(kr + i * 16 + 8);
          float4 k3 = *(const float4*)(kr + i * 16 + 12);
          d0 += qv[i*16+ 0]*k0.x + qv[i*16+ 1]*k0.y + qv[i*16+ 2]*k0.z + qv[i*16+ 3]*k0.w;
          d1 += qv[i*16+ 4]*k1.x + qv[i*16+ 5]*k1.y + qv[i*16+ 6]*k1.z + qv[i*16+ 7]*k1.w;
          d2 += qv[i*16+ 8]*k2.x + qv[i*16+ 9]*k2.y + qv[i*16+10]*k2.z + qv[i*16+11]*k2.w;
          d3 += qv[i*16+12]*k3.x + qv[i*16+13]*k3.y + qv[i*16+14]*k3.z + qv[i*16+15]*k3.w;
        }
        s[jj] = ((d0 + d1) + (d2 + d3)) * 0.125f;
        subm = fmaxf(subm, s[jj]);
      }
      float mnew = fmaxf(m, subm);
      float corr = __expf(m - mnew);   // 1.0 when max unchanged; 0 on first tile
      l *= corr;
#pragma unroll
      for (int i = 0; i < 64; i++) acc[i] *= corr;
#pragma unroll
      for (int jj = 0; jj < 16; jj++) {
        float p = __expf(s[jj] - mnew);
        l += p;
        const float* vr = Vs + (sub * 16 + jj) * 64;
#pragma unroll
        for (int i = 0; i < 16; i++) {
          float4 vv = *(const float4*)(vr + i * 4);
          acc[i * 4 + 0] += p * vv.x;
          acc[i * 4 + 1] += p * vv.y;
          acc[i * 4 + 2] += p * vv.z;
          acc[i * 4 + 3] += p * vv.w;
        }
      }
      m = mnew;
    }
  }

  float inv = 1.0f / l;
  float* orow = O + ((size_t)bi * SEQ + li) * DIM + n * HEADD;
#pragma unroll
  for (int i = 0; i < 16; i++) {
    float4 v = make_float4(acc[i*4+0]*inv, acc[i*4+1]*inv, acc[i*4+2]*inv, acc[i*4+3]*inv);
    *(float4*)(orow + i * 4) = v;
  }
}

// ---------------- launch ----------------
extern "C" void kernel_launch(void* const* d_in, const int* in_sizes, int n_in,
                              void* d_out, int out_size, void* d_ws, size_t ws_size,
                              hipStream_t stream) {
  const float* x    = (const float*)d_in[0];
  const float* Wq   = (const float*)d_in[1];
  const float* Wk   = (const float*)d_in[2];
  const float* Wv   = (const float*)d_in[3];
  const float* Wo   = (const float*)d_in[4];
  const float* W1   = (const float*)d_in[5];
  const float* b1   = (const float*)d_in[6];
  const float* W2   = (const float*)d_in[7];
  const float* b2   = (const float*)d_in[8];
  const float* gln1 = (const float*)d_in[9];
  const float* bln1 = (const float*)d_in[10];
  const float* gln2 = (const float*)d_in[11];
  const float* bln2 = (const float*)d_in[12];
  float* out = (float*)d_out;
  float* ws  = (float*)d_ws;

  const size_t MEG = 1u << 20;
  float* Qb = ws + 0 * MEG;    // 4M floats
  float* Kb = ws + 4 * MEG;
  float* Vb = ws + 8 * MEG;
  float* Hb = ws + 12 * MEG;   // h (LN1 out), later reused for attention output o
  float* X2 = ws + 16 * MEG;   // x + o@Wo
  float* F1 = ws + 20 * MEG;   // gelu(h2@W1+b1): 16M floats
  // total ws use: 36M floats = 144 MB

  // 1. h = LN(x)
  ln_kernel<<<4096, 256, 0, stream>>>(x, gln1, bln1, Hb);
  // 2. Q,K,V = h @ {Wq,Wk,Wv}
  qkv_kernel<<<dim3(8, 32, 3), 256, 0, stream>>>(Hb, Wq, Wk, Wv, Qb, Kb, Vb);
  // 3. o = attention(Q,K,V)  (writes into Hb; h no longer needed)
  attn_kernel<<<dim3(4, 16, 4), 256, 0, stream>>>(Qb, Kb, Vb, Hb);
  // 4. x2 = x + o @ Wo
  gemm_kernel<false, true, false><<<dim3(8, 32), 256, 0, stream>>>(
      Hb, Wo, nullptr, x, X2, 4096, DIM, DIM);
  // 5. h2 = LN(x2)  (into Qb; q no longer needed)
  ln_kernel<<<4096, 256, 0, stream>>>(X2, gln2, bln2, Qb);
  // 6. f1 = gelu(h2 @ W1 + b1)
  gemm_kernel<true, false, true><<<dim3(32, 32), 256, 0, stream>>>(
      Qb, W1, b1, nullptr, F1, 4096, MLP_DIM, DIM);
  // 7. out = x2 + f1 @ W2 + b2
  gemm_kernel<true, true, false><<<dim3(8, 32), 256, 0, stream>>>(
      F1, W2, b2, X2, out, 4096, DIM, MLP_DIM);
}

// Round 2
// 1817.176 us; speedup vs baseline: 1.2344x; 1.2344x over previous
//
#include <hip/hip_runtime.h>
#include <math.h>

#define DIM 1024
#define SEQ 1024
#define BATCH 4
#define NHEADS 16
#define HEADD 64
#define MLP_DIM 4096

// ---------------- LayerNorm: one block per row (rows = 4096) ----------------
__global__ __launch_bounds__(256) void ln_kernel(const float* __restrict__ x,
                                                 const float* __restrict__ g,
                                                 const float* __restrict__ b,
                                                 float* __restrict__ out) {
  int row = blockIdx.x;
  int t = threadIdx.x;
  const float* xr = x + (size_t)row * DIM;
  float4 v = *(const float4*)(xr + t * 4);
  float s  = v.x + v.y + v.z + v.w;
  float sq = v.x * v.x + v.y * v.y + v.z * v.z + v.w * v.w;
#pragma unroll
  for (int off = 32; off > 0; off >>= 1) {
    s  += __shfl_down(s, off);
    sq += __shfl_down(sq, off);
  }
  __shared__ float red_s[4], red_q[4];
  __shared__ float mu_s, inv_s;
  int wid = t >> 6;
  if ((t & 63) == 0) { red_s[wid] = s; red_q[wid] = sq; }
  __syncthreads();
  if (t == 0) {
    float S  = red_s[0] + red_s[1] + red_s[2] + red_s[3];
    float Sq = red_q[0] + red_q[1] + red_q[2] + red_q[3];
    float mu  = S * (1.0f / DIM);
    float var = Sq * (1.0f / DIM) - mu * mu;
    mu_s  = mu;
    inv_s = 1.0f / sqrtf(var + 1e-5f);
  }
  __syncthreads();
  float mu = mu_s, inv = inv_s;
  float4 gv = *(const float4*)(g + t * 4);
  float4 bv = *(const float4*)(b + t * 4);
  float4 o;
  o.x = (v.x - mu) * inv * gv.x + bv.x;
  o.y = (v.y - mu) * inv * gv.y + bv.y;
  o.z = (v.z - mu) * inv * gv.z + bv.z;
  o.w = (v.w - mu) * inv * gv.w + bv.w;
  *(float4*)(out + (size_t)row * DIM + t * 4) = o;
}

// ---------------- fp32 SIMT GEMM: (64*MQUAD)x128 tile, BK=16, 256 threads ---
// C(MxN) = A(MxK) @ B(KxN)  [+ bias[col]] [gelu] [+ res[row*N+col]]
template <int MQUAD, bool BIAS, bool RES, bool GELU>
__device__ __forceinline__ void gemm_body(const float* __restrict__ A,
                                          const float* __restrict__ B,
                                          const float* __restrict__ bias,
                                          const float* __restrict__ res,
                                          float* __restrict__ C,
                                          int M, int N, int K) {
  __shared__ float As[16][64 * MQUAD];
  __shared__ float Bs[16][128];
  const int t  = threadIdx.x;
  const int tx = t & 15;   // N direction
  const int ty = t >> 4;   // M direction
  const int m0 = blockIdx.y * (64 * MQUAD);
  const int n0 = blockIdx.x * 128;
  float acc[MQUAD][2][4][4] = {};
  const float* Aptr = A + (size_t)m0 * K;
  const float* Bptr = B + n0;

  for (int k0 = 0; k0 < K; k0 += 16) {
#pragma unroll
    for (int i = 0; i < MQUAD; i++) {
      int f = t + i * 256;                 // 256*MQUAD float4 of A tile
      int row = f >> 2, quad = f & 3;
      float4 va = *(const float4*)(Aptr + (size_t)row * K + k0 + quad * 4);
      As[quad * 4 + 0][row] = va.x;
      As[quad * 4 + 1][row] = va.y;
      As[quad * 4 + 2][row] = va.z;
      As[quad * 4 + 3][row] = va.w;
    }
#pragma unroll
    for (int i = 0; i < 2; i++) {
      int f = t + i * 256;                 // 512 float4 of B tile
      int row = f >> 5, c4 = (f & 31) * 4;
      *(float4*)&Bs[row][c4] = *(const float4*)(Bptr + (size_t)(k0 + row) * N + c4);
    }
    __syncthreads();
#pragma unroll
    for (int k = 0; k < 16; k++) {
      float av[MQUAD][4];
#pragma unroll
      for (int qr = 0; qr < MQUAD; qr++) {
        float4 a = *(const float4*)&As[k][qr * 64 + ty * 4];
        av[qr][0] = a.x; av[qr][1] = a.y; av[qr][2] = a.z; av[qr][3] = a.w;
      }
      float4 b0 = *(const float4*)&Bs[k][tx * 4];
      float4 b1 = *(const float4*)&Bs[k][64 + tx * 4];
      float bv[2][4] = {{b0.x, b0.y, b0.z, b0.w}, {b1.x, b1.y, b1.z, b1.w}};
#pragma unroll
      for (int qr = 0; qr < MQUAD; qr++)
#pragma unroll
        for (int r = 0; r < 4; r++)
#pragma unroll
          for (int qc = 0; qc < 2; qc++)
#pragma unroll
            for (int c = 0; c < 4; c++)
              acc[qr][qc][r][c] += av[qr][r] * bv[qc][c];
    }
    __syncthreads();
  }

#pragma unroll
  for (int qr = 0; qr < MQUAD; qr++) {
#pragma unroll
    for (int r = 0; r < 4; r++) {
      int row = m0 + qr * 64 + ty * 4 + r;
#pragma unroll
      for (int qc = 0; qc < 2; qc++) {
        int col = n0 + qc * 64 + tx * 4;
        float4 v = make_float4(acc[qr][qc][r][0], acc[qr][qc][r][1],
                               acc[qr][qc][r][2], acc[qr][qc][r][3]);
        if (BIAS) {
          float4 bb = *(const float4*)(bias + col);
          v.x += bb.x; v.y += bb.y; v.z += bb.z; v.w += bb.w;
        }
        if (GELU) {
          v.x = 0.5f * v.x * (1.0f + erff(v.x * 0.70710678118654752f));
          v.y = 0.5f * v.y * (1.0f + erff(v.y * 0.70710678118654752f));
          v.z = 0.5f * v.z * (1.0f + erff(v.z * 0.70710678118654752f));
          v.w = 0.5f * v.w * (1.0f + erff(v.w * 0.70710678118654752f));
        }
        if (RES) {
          float4 rr = *(const float4*)(res + (size_t)row * N + col);
          v.x += rr.x; v.y += rr.y; v.z += rr.z; v.w += rr.w;
        }
        *(float4*)(C + (size_t)row * N + col) = v;
      }
    }
  }
}

template <int MQUAD, bool BIAS, bool RES, bool GELU>
__global__ __launch_bounds__(256, 2) void gemm_kernel(const float* __restrict__ A,
                                                      const float* __restrict__ B,
                                                      const float* __restrict__ bias,
                                                      const float* __restrict__ res,
                                                      float* __restrict__ C,
                                                      int M, int N, int K) {
  gemm_body<MQUAD, BIAS, RES, GELU>(A, B, bias, res, C, M, N, K);
}

// fused QKV: blockIdx.z selects weight/output (one launch, 768 blocks)
__global__ __launch_bounds__(256, 2) void qkv_kernel(const float* __restrict__ A,
                                                     const float* __restrict__ Wq,
                                                     const float* __restrict__ Wk,
                                                     const float* __restrict__ Wv,
                                                     float* __restrict__ Qo,
                                                     float* __restrict__ Ko,
                                                     float* __restrict__ Vo) {
  const float* B = (blockIdx.z == 0) ? Wq : (blockIdx.z == 1) ? Wk : Wv;
  float* C = (blockIdx.z == 0) ? Qo : (blockIdx.z == 1) ? Ko : Vo;
  gemm_body<2, false, false, false>(A, B, nullptr, nullptr, C, 4096, DIM, DIM);
}

// ---------------- attention ----------------
// Per (batch b, head n): Qh = Qmat[b, n*64:(n+1)*64, :] (contiguous 64*1024
// floats) reinterpreted as (1024, 64) row-major (faithful to torch .view).
// 4 threads cooperate per query row (16 head-dims each); 64 q-rows per block;
// grid (16,16,4)=1024 blocks = 4/CU. KV tiles of 64 rows in 32 KB LDS.
#define KVT 64
__global__ __launch_bounds__(256, 4) void attn_kernel(const float* __restrict__ Q,
                                                      const float* __restrict__ K,
                                                      const float* __restrict__ V,
                                                      float* __restrict__ O) {
  const int qt = blockIdx.x;   // 0..15
  const int n  = blockIdx.y;   // 0..15
  const int bi = blockIdx.z;   // 0..3
  const size_t headoff = ((size_t)bi * SEQ + (size_t)n * HEADD) * DIM;
  const float* Qh = Q + headoff;
  const float* Kh = K + headoff;
  const float* Vh = V + headoff;
  const int t    = threadIdx.x;
  const int qr   = t >> 2;     // local q-row 0..63
  const int quad = t & 3;      // 16-dim segment 0..3
  const int li   = qt * 64 + qr;

  float qv[16];
#pragma unroll
  for (int i = 0; i < 4; i++) {
    float4 v = *(const float4*)(Qh + (size_t)li * 64 + quad * 16 + i * 4);
    qv[i * 4 + 0] = v.x; qv[i * 4 + 1] = v.y;
    qv[i * 4 + 2] = v.z; qv[i * 4 + 3] = v.w;
  }
  float acc[16] = {};
  float m = -1e30f, l = 0.0f;

  __shared__ float Ks[KVT * 64];
  __shared__ float Vs[KVT * 64];

  for (int kt = 0; kt < SEQ / KVT; kt++) {
    __syncthreads();   // previous tile fully consumed
    const float4* Ksrc = (const float4*)(Kh + (size_t)kt * KVT * 64);
    const float4* Vsrc = (const float4*)(Vh + (size_t)kt * KVT * 64);
    float4* Kdst = (float4*)Ks;
    float4* Vdst = (float4*)Vs;
#pragma unroll
    for (int i = 0; i < 4; i++) {
      Kdst[t + i * 256] = Ksrc[t + i * 256];
      Vdst[t + i * 256] = Vsrc[t + i * 256];
    }
    __syncthreads();

#pragma unroll
    for (int sub = 0; sub < KVT / 16; sub++) {
      float s[16];
      float subm = -1e30f;
#pragma unroll
      for (int jj = 0; jj < 16; jj++) {
        const float* kr = Ks + (sub * 16 + jj) * 64 + quad * 16;
        float4 k0 = *(const float4*)(kr + 0);
        float4 k1 = *(const float4*)(kr + 4);
        float4 k2 = *(const float4*)(kr + 8);
        float4 k3 = *(const float4*)(kr + 12);
        float d0 = qv[ 0]*k0.x + qv[ 1]*k0.y + qv[ 2]*k0.z + qv[ 3]*k0.w;
        float d1 = qv[ 4]*k1.x + qv[ 5]*k1.y + qv[ 6]*k1.z + qv[ 7]*k1.w;
        float d2 = qv[ 8]*k2.x + qv[ 9]*k2.y + qv[10]*k2.z + qv[11]*k2.w;
        float d3 = qv[12]*k3.x + qv[13]*k3.y + qv[14]*k3.z + qv[15]*k3.w;
        float partial = (d0 + d1) + (d2 + d3);
        partial += __shfl_xor(partial, 1);
        partial += __shfl_xor(partial, 2);
        s[jj] = partial * 0.125f;
        subm = fmaxf(subm, s[jj]);
      }
      float mnew = fmaxf(m, subm);
      float corr = __expf(m - mnew);   // 1.0 when max unchanged; 0 on first tile
      l *= corr;
#pragma unroll
      for (int i = 0; i < 16; i++) acc[i] *= corr;
#pragma unroll
      for (int jj = 0; jj < 16; jj++) {
        float p = __expf(s[jj] - mnew);
        l += p;
        const float* vr = Vs + (sub * 16 + jj) * 64 + quad * 16;
#pragma unroll
        for (int i = 0; i < 4; i++) {
          float4 vv = *(const float4*)(vr + i * 4);
          acc[i * 4 + 0] += p * vv.x;
          acc[i * 4 + 1] += p * vv.y;
          acc[i * 4 + 2] += p * vv.z;
          acc[i * 4 + 3] += p * vv.w;
        }
      }
      m = mnew;
    }
  }

  float inv = 1.0f / l;
  float* orow = O + ((size_t)bi * SEQ + li) * DIM + n * HEADD + quad * 16;
#pragma unroll
  for (int i = 0; i < 4; i++) {
    float4 v = make_float4(acc[i*4+0]*inv, acc[i*4+1]*inv,
                           acc[i*4+2]*inv, acc[i*4+3]*inv);
    *(float4*)(orow + i * 4) = v;
  }
}

// ---------------- launch ----------------
extern "C" void kernel_launch(void* const* d_in, const int* in_sizes, int n_in,
                              void* d_out, int out_size, void* d_ws, size_t ws_size,
                              hipStream_t stream) {
  const float* x    = (const float*)d_in[0];
  const float* Wq   = (const float*)d_in[1];
  const float* Wk   = (const float*)d_in[2];
  const float* Wv   = (const float*)d_in[3];
  const float* Wo   = (const float*)d_in[4];
  const float* W1   = (const float*)d_in[5];
  const float* b1   = (const float*)d_in[6];
  const float* W2   = (const float*)d_in[7];
  const float* b2   = (const float*)d_in[8];
  const float* gln1 = (const float*)d_in[9];
  const float* bln1 = (const float*)d_in[10];
  const float* gln2 = (const float*)d_in[11];
  const float* bln2 = (const float*)d_in[12];
  float* out = (float*)d_out;
  float* ws  = (float*)d_ws;

  const size_t MEG = 1u << 20;
  float* Qb = ws + 0 * MEG;    // 4M floats
  float* Kb = ws + 4 * MEG;
  float* Vb = ws + 8 * MEG;
  float* Hb = ws + 12 * MEG;   // h (LN1 out), later reused for attention output o
  float* X2 = ws + 16 * MEG;   // x + o@Wo
  float* F1 = ws + 20 * MEG;   // gelu(h2@W1+b1): 16M floats
  // total ws use: 36M floats = 144 MB

  // 1. h = LN(x)
  ln_kernel<<<4096, 256, 0, stream>>>(x, gln1, bln1, Hb);
  // 2. Q,K,V = h @ {Wq,Wk,Wv}
  qkv_kernel<<<dim3(8, 32, 3), 256, 0, stream>>>(Hb, Wq, Wk, Wv, Qb, Kb, Vb);
  // 3. o = attention(Q,K,V)  (writes into Hb; h no longer needed)
  attn_kernel<<<dim3(16, 16, 4), 256, 0, stream>>>(Qb, Kb, Vb, Hb);
  // 4. x2 = x + o @ Wo   (BM=64 tile: 512 blocks = 2/CU)
  gemm_kernel<1, false, true, false><<<dim3(8, 64), 256, 0, stream>>>(
      Hb, Wo, nullptr, x, X2, 4096, DIM, DIM);
  // 5. h2 = LN(x2)  (into Qb; q no longer needed)
  ln_kernel<<<4096, 256, 0, stream>>>(X2, gln2, bln2, Qb);
  // 6. f1 = gelu(h2 @ W1 + b1)  (1024 blocks = 4/CU already)
  gemm_kernel<2, true, false, true><<<dim3(32, 32), 256, 0, stream>>>(
      Qb, W1, b1, nullptr, F1, 4096, MLP_DIM, DIM);
  // 7. out = x2 + f1 @ W2 + b2  (BM=64 tile: 512 blocks = 2/CU)
  gemm_kernel<1, true, true, false><<<dim3(8, 64), 256, 0, stream>>>(
      F1, W2, b2, X2, out, 4096, DIM, MLP_DIM);
}

// Round 4
// 1090.666 us; speedup vs baseline: 2.0567x; 1.6661x over previous
//
#include <hip/hip_runtime.h>
#include <math.h>

#define DIM 1024
#define SEQ 1024
#define BATCH 4
#define NHEADS 16
#define HEADD 64
#define MLP_DIM 4096

typedef short short8 __attribute__((ext_vector_type(8)));
typedef float f32x4 __attribute__((ext_vector_type(4)));
#define MFMA(a, b, c) __builtin_amdgcn_mfma_f32_16x16x32_bf16(a, b, c, 0, 0, 0)

__device__ __forceinline__ ushort f2b(float x) {
  unsigned u = __float_as_uint(x);
  unsigned r = (u + 0x7FFFu + ((u >> 16) & 1u)) >> 16;
  return (ushort)r;
}
__device__ __forceinline__ float b2f(ushort h) {
  return __uint_as_float(((unsigned)h) << 16);
}

__device__ __forceinline__ void g2l16(const void* g, void* l) {
  __builtin_amdgcn_global_load_lds((const __attribute__((address_space(1))) void*)g,
                                   (__attribute__((address_space(3))) void*)l, 16, 0, 0);
}

// ---------------- LayerNorm -> bf16 hi/lo ----------------
__global__ __launch_bounds__(256) void ln_kernel(const float* __restrict__ x,
                                                 const float* __restrict__ g,
                                                 const float* __restrict__ b,
                                                 ushort* __restrict__ ohi,
                                                 ushort* __restrict__ olo) {
  int row = blockIdx.x;
  int t = threadIdx.x;
  const float* xr = x + (size_t)row * DIM;
  float4 v = *(const float4*)(xr + t * 4);
  float s  = v.x + v.y + v.z + v.w;
  float sq = v.x * v.x + v.y * v.y + v.z * v.z + v.w * v.w;
#pragma unroll
  for (int off = 32; off > 0; off >>= 1) {
    s  += __shfl_down(s, off);
    sq += __shfl_down(sq, off);
  }
  __shared__ float red_s[4], red_q[4];
  __shared__ float mu_s, inv_s;
  int wid = t >> 6;
  if ((t & 63) == 0) { red_s[wid] = s; red_q[wid] = sq; }
  __syncthreads();
  if (t == 0) {
    float S  = red_s[0] + red_s[1] + red_s[2] + red_s[3];
    float Sq = red_q[0] + red_q[1] + red_q[2] + red_q[3];
    float mu  = S * (1.0f / DIM);
    float var = Sq * (1.0f / DIM) - mu * mu;
    mu_s  = mu;
    inv_s = 1.0f / sqrtf(var + 1e-5f);
  }
  __syncthreads();
  float mu = mu_s, inv = inv_s;
  float4 gv = *(const float4*)(g + t * 4);
  float4 bv = *(const float4*)(b + t * 4);
  float o0 = (v.x - mu) * inv * gv.x + bv.x;
  float o1 = (v.y - mu) * inv * gv.y + bv.y;
  float o2 = (v.z - mu) * inv * gv.z + bv.z;
  float o3 = (v.w - mu) * inv * gv.w + bv.w;
  ushort4 hv, lv;
  hv.x = f2b(o0); lv.x = f2b(o0 - b2f(hv.x));
  hv.y = f2b(o1); lv.y = f2b(o1 - b2f(hv.y));
  hv.z = f2b(o2); lv.z = f2b(o2 - b2f(hv.z));
  hv.w = f2b(o3); lv.w = f2b(o3 - b2f(hv.w));
  *(ushort4*)(ohi + (size_t)row * DIM + t * 4) = hv;
  *(ushort4*)(olo + (size_t)row * DIM + t * 4) = lv;
}

// ---------------- weight prep: transpose KxN fp32 -> NxK bf16 hi/lo --------
__global__ __launch_bounds__(256) void wprep_kernel(const float* __restrict__ W,
                                                    ushort* __restrict__ Whi,
                                                    ushort* __restrict__ Wlo,
                                                    int Kd, int Nd) {
  __shared__ float tile[64][65];
  const int t = threadIdx.x;
  const int n0 = blockIdx.x * 64, k0 = blockIdx.y * 64;
  const int r = t >> 4, c4 = (t & 15) * 4;
#pragma unroll
  for (int i = 0; i < 4; i++) {
    float4 v = *(const float4*)&W[(size_t)(k0 + r + i * 16) * Nd + n0 + c4];
    tile[r + i * 16][c4 + 0] = v.x;
    tile[r + i * 16][c4 + 1] = v.y;
    tile[r + i * 16][c4 + 2] = v.z;
    tile[r + i * 16][c4 + 3] = v.w;
  }
  __syncthreads();
#pragma unroll
  for (int i = 0; i < 4; i++) {
    int nr = r + i * 16;
    float x0 = tile[c4 + 0][nr], x1 = tile[c4 + 1][nr];
    float x2 = tile[c4 + 2][nr], x3 = tile[c4 + 3][nr];
    ushort4 hv, lv;
    hv.x = f2b(x0); lv.x = f2b(x0 - b2f(hv.x));
    hv.y = f2b(x1); lv.y = f2b(x1 - b2f(hv.y));
    hv.z = f2b(x2); lv.z = f2b(x2 - b2f(hv.z));
    hv.w = f2b(x3); lv.w = f2b(x3 - b2f(hv.w));
    *(ushort4*)&Whi[(size_t)(n0 + nr) * Kd + k0 + c4] = hv;
    *(ushort4*)&Wlo[(size_t)(n0 + nr) * Kd + k0 + c4] = lv;
  }
}

// ---------------- split-bf16 MFMA GEMM ----------------
// C(MxN) = (Ahi+Alo)(MxK) @ (Bhi+Blo)^T  with B stored N x K row-major.
// 3-pass: Ahi*Bhi + Ahi*Blo + Alo*Bhi. Block: 4 waves as 2x2,
// BM=32*MS, BN=32*NS, BK=32. Fragment-ordered LDS staging via global_load_lds:
// lane l loads row (sub*16 + l%16), k (l/16)*8..+8 -> LDS slot + l*16B, which
// is exactly the mfma_f32_16x16x32_bf16 A/B fragment layout (conflict-free).
// EPI: 0=store f32; 1=+res f32; 2=+bias,gelu -> bf16 hi/lo; 3=+bias+res f32.
template <int MS, int NS, int EPI>
__device__ __forceinline__ void mgemm_body(
    const ushort* __restrict__ Ahi, const ushort* __restrict__ Alo,
    const ushort* __restrict__ Bhi, const ushort* __restrict__ Blo,
    const float* __restrict__ bias, const float* __restrict__ res,
    float* __restrict__ Cf, ushort* __restrict__ Chi, ushort* __restrict__ Clo,
    int M, int N, int K) {
  constexpr int ASUB = 2 * MS;          // BM/16
  constexpr int BSUB = 2 * NS;          // BN/16
  constexpr int TOT = 2 * (ASUB + BSUB);
  constexpr int PW = TOT / 4;
  __shared__ ushort lds[TOT * 512];

  const int t = threadIdx.x;
  const int l = t & 63;
  const int wid = t >> 6;
  const int wm = wid >> 1, wn = wid & 1;
  const int m0 = blockIdx.y * (ASUB * 16);
  const int n0 = blockIdx.x * (BSUB * 16);
  const int lr = l & 15;
  const int lk = (l >> 4) * 8;

  const ushort* gsrc[PW];
  ushort* ldst[PW];
#pragma unroll
  for (int i = 0; i < PW; i++) {
    int j = wid * PW + i;
    const ushort* base;
    int rowbase, slot;
    if (j < 2 * ASUB) {
      int plane = j & 1, sub = j >> 1;
      base = plane ? Alo : Ahi;
      rowbase = m0 + sub * 16;
      slot = plane * ASUB + sub;
    } else {
      int jb = j - 2 * ASUB;
      int plane = jb & 1, sub = jb >> 1;
      base = plane ? Blo : Bhi;
      rowbase = n0 + sub * 16;
      slot = 2 * ASUB + plane * BSUB + sub;
    }
    gsrc[i] = base + (size_t)(rowbase + lr) * K + lk;
    ldst[i] = &lds[slot * 512];
  }

  f32x4 acc[MS][NS] = {};

  for (int k0 = 0; k0 < K; k0 += 32) {
    __syncthreads();
#pragma unroll
    for (int i = 0; i < PW; i++) {
      g2l16(gsrc[i], ldst[i]);
      gsrc[i] += 32;
    }
    __syncthreads();   // compiler drains vmcnt(0) here (loads landed)

    short8 ah[MS], al[MS], bh[NS], bl[NS];
#pragma unroll
    for (int mi = 0; mi < MS; mi++) {
      ah[mi] = *(const short8*)&lds[(wm * MS + mi) * 512 + l * 8];
      al[mi] = *(const short8*)&lds[(ASUB + wm * MS + mi) * 512 + l * 8];
    }
#pragma unroll
    for (int ni = 0; ni < NS; ni++) {
      bh[ni] = *(const short8*)&lds[(2 * ASUB + wn * NS + ni) * 512 + l * 8];
      bl[ni] = *(const short8*)&lds[(2 * ASUB + BSUB + wn * NS + ni) * 512 + l * 8];
    }
#pragma unroll
    for (int mi = 0; mi < MS; mi++)
#pragma unroll
      for (int ni = 0; ni < NS; ni++) {
        acc[mi][ni] = MFMA(ah[mi], bh[ni], acc[mi][ni]);
        acc[mi][ni] = MFMA(ah[mi], bl[ni], acc[mi][ni]);
        acc[mi][ni] = MFMA(al[mi], bh[ni], acc[mi][ni]);
      }
  }

  const int orow0 = m0 + wm * (MS * 16);
  const int ocol0 = n0 + wn * (NS * 16);
#pragma unroll
  for (int mi = 0; mi < MS; mi++) {
#pragma unroll
    for (int r = 0; r < 4; r++) {
      int row = orow0 + mi * 16 + (l >> 4) * 4 + r;
#pragma unroll
      for (int ni = 0; ni < NS; ni++) {
        int col = ocol0 + ni * 16 + lr;
        size_t idx = (size_t)row * N + col;
        float v = acc[mi][ni][r];
        if (EPI == 0) {
          Cf[idx] = v;
        } else if (EPI == 1) {
          Cf[idx] = v + res[idx];
        } else if (EPI == 2) {
          v += bias[col];
          v = 0.5f * v * (1.0f + erff(v * 0.70710678118654752f));
          ushort h = f2b(v);
          Chi[idx] = h;
          Clo[idx] = f2b(v - b2f(h));
        } else {
          Cf[idx] = v + bias[col] + res[idx];
        }
      }
    }
  }
}

template <int MS, int NS, int EPI>
__global__ __launch_bounds__(256, 2) void mgemm_kernel(
    const ushort* __restrict__ Ahi, const ushort* __restrict__ Alo,
    const ushort* __restrict__ Bhi, const ushort* __restrict__ Blo,
    const float* __restrict__ bias, const float* __restrict__ res,
    float* __restrict__ Cf, ushort* __restrict__ Chi, ushort* __restrict__ Clo,
    int M, int N, int K) {
  mgemm_body<MS, NS, EPI>(Ahi, Alo, Bhi, Blo, bias, res, Cf, Chi, Clo, M, N, K);
}

// fused QKV: z selects weight/output (768 blocks = 3/CU)
__global__ __launch_bounds__(256, 2) void qkv_mfma(
    const ushort* __restrict__ Ahi, const ushort* __restrict__ Alo,
    const ushort* __restrict__ Wqh, const ushort* __restrict__ Wql,
    const ushort* __restrict__ Wkh, const ushort* __restrict__ Wkl,
    const ushort* __restrict__ Wvh, const ushort* __restrict__ Wvl,
    float* __restrict__ Qo, float* __restrict__ Ko, float* __restrict__ Vo) {
  const ushort* bh = (blockIdx.z == 0) ? Wqh : (blockIdx.z == 1) ? Wkh : Wvh;
  const ushort* bl = (blockIdx.z == 0) ? Wql : (blockIdx.z == 1) ? Wkl : Wvl;
  float* C = (blockIdx.z == 0) ? Qo : (blockIdx.z == 1) ? Ko : Vo;
  mgemm_body<4, 4, 0>(Ahi, Alo, bh, bl, nullptr, nullptr, C, nullptr, nullptr,
                      4096, DIM, DIM);
}

// ---------------- attention (fp32, unchanged math; bf16 hi/lo output) ------
#define KVT 64
__global__ __launch_bounds__(256, 4) void attn_kernel(const float* __restrict__ Q,
                                                      const float* __restrict__ K,
                                                      const float* __restrict__ V,
                                                      ushort* __restrict__ Ohi,
                                                      ushort* __restrict__ Olo) {
  const int qt = blockIdx.x;
  const int n  = blockIdx.y;
  const int bi = blockIdx.z;
  const size_t headoff = ((size_t)bi * SEQ + (size_t)n * HEADD) * DIM;
  const float* Qh = Q + headoff;
  const float* Kh = K + headoff;
  const float* Vh = V + headoff;
  const int t    = threadIdx.x;
  const int qr   = t >> 2;
  const int quad = t & 3;
  const int li   = qt * 64 + qr;

  float qv[16];
#pragma unroll
  for (int i = 0; i < 4; i++) {
    float4 v = *(const float4*)(Qh + (size_t)li * 64 + quad * 16 + i * 4);
    qv[i * 4 + 0] = v.x; qv[i * 4 + 1] = v.y;
    qv[i * 4 + 2] = v.z; qv[i * 4 + 3] = v.w;
  }
  float acc[16] = {};
  float m = -1e30f, l = 0.0f;

  __shared__ float Ks[KVT * 64];
  __shared__ float Vs[KVT * 64];

  for (int kt = 0; kt < SEQ / KVT; kt++) {
    __syncthreads();
    const float4* Ksrc = (const float4*)(Kh + (size_t)kt * KVT * 64);
    const float4* Vsrc = (const float4*)(Vh + (size_t)kt * KVT * 64);
    float4* Kdst = (float4*)Ks;
    float4* Vdst = (float4*)Vs;
#pragma unroll
    for (int i = 0; i < 4; i++) {
      Kdst[t + i * 256] = Ksrc[t + i * 256];
      Vdst[t + i * 256] = Vsrc[t + i * 256];
    }
    __syncthreads();

#pragma unroll
    for (int sub = 0; sub < KVT / 16; sub++) {
      float s[16];
      float subm = -1e30f;
#pragma unroll
      for (int jj = 0; jj < 16; jj++) {
        const float* kr = Ks + (sub * 16 + jj) * 64 + quad * 16;
        float4 k0 = *(const float4*)(kr + 0);
        float4 k1 = *(const float4*)(kr + 4);
        float4 k2 = *(const float4*)(kr + 8);
        float4 k3 = *(const float4*)(kr + 12);
        float d0 = qv[ 0]*k0.x + qv[ 1]*k0.y + qv[ 2]*k0.z + qv[ 3]*k0.w;
        float d1 = qv[ 4]*k1.x + qv[ 5]*k1.y + qv[ 6]*k1.z + qv[ 7]*k1.w;
        float d2 = qv[ 8]*k2.x + qv[ 9]*k2.y + qv[10]*k2.z + qv[11]*k2.w;
        float d3 = qv[12]*k3.x + qv[13]*k3.y + qv[14]*k3.z + qv[15]*k3.w;
        float partial = (d0 + d1) + (d2 + d3);
        partial += __shfl_xor(partial, 1);
        partial += __shfl_xor(partial, 2);
        s[jj] = partial * 0.125f;
        subm = fmaxf(subm, s[jj]);
      }
      float mnew = fmaxf(m, subm);
      float corr = __expf(m - mnew);
      l *= corr;
#pragma unroll
      for (int i = 0; i < 16; i++) acc[i] *= corr;
#pragma unroll
      for (int jj = 0; jj < 16; jj++) {
        float p = __expf(s[jj] - mnew);
        l += p;
        const float* vr = Vs + (sub * 16 + jj) * 64 + quad * 16;
#pragma unroll
        for (int i = 0; i < 4; i++) {
          float4 vv = *(const float4*)(vr + i * 4);
          acc[i * 4 + 0] += p * vv.x;
          acc[i * 4 + 1] += p * vv.y;
          acc[i * 4 + 2] += p * vv.z;
          acc[i * 4 + 3] += p * vv.w;
        }
      }
      m = mnew;
    }
  }

  float inv = 1.0f / l;
  size_t obase = ((size_t)bi * SEQ + li) * DIM + n * HEADD + quad * 16;
#pragma unroll
  for (int i = 0; i < 4; i++) {
    float v0 = acc[i*4+0]*inv, v1 = acc[i*4+1]*inv;
    float v2 = acc[i*4+2]*inv, v3 = acc[i*4+3]*inv;
    ushort4 hv, lv;
    hv.x = f2b(v0); lv.x = f2b(v0 - b2f(hv.x));
    hv.y = f2b(v1); lv.y = f2b(v1 - b2f(hv.y));
    hv.z = f2b(v2); lv.z = f2b(v2 - b2f(hv.z));
    hv.w = f2b(v3); lv.w = f2b(v3 - b2f(hv.w));
    *(ushort4*)(Ohi + obase + i * 4) = hv;
    *(ushort4*)(Olo + obase + i * 4) = lv;
  }
}

// ---------------- launch ----------------
extern "C" void kernel_launch(void* const* d_in, const int* in_sizes, int n_in,
                              void* d_out, int out_size, void* d_ws, size_t ws_size,
                              hipStream_t stream) {
  const float* x    = (const float*)d_in[0];
  const float* Wq   = (const float*)d_in[1];
  const float* Wk   = (const float*)d_in[2];
  const float* Wv   = (const float*)d_in[3];
  const float* Wo   = (const float*)d_in[4];
  const float* W1   = (const float*)d_in[5];
  const float* b1   = (const float*)d_in[6];
  const float* W2   = (const float*)d_in[7];
  const float* b2   = (const float*)d_in[8];
  const float* gln1 = (const float*)d_in[9];
  const float* bln1 = (const float*)d_in[10];
  const float* gln2 = (const float*)d_in[11];
  const float* bln2 = (const float*)d_in[12];
  float* out = (float*)d_out;
  char* W = (char*)d_ws;

  // ---- workspace layout (MB offsets, 144 MB total; lifetimes disjoint) ----
  const size_t MB = 1u << 20;
  ushort* Wqh = (ushort*)(W + 0 * MB);
  ushort* Wql = (ushort*)(W + 2 * MB);
  ushort* Wkh = (ushort*)(W + 4 * MB);
  ushort* Wkl = (ushort*)(W + 6 * MB);
  ushort* Wvh = (ushort*)(W + 8 * MB);
  ushort* Wvl = (ushort*)(W + 10 * MB);
  ushort* Woh = (ushort*)(W + 12 * MB);
  ushort* Wol = (ushort*)(W + 14 * MB);
  ushort* W1h = (ushort*)(W + 16 * MB);
  ushort* W1l = (ushort*)(W + 24 * MB);
  ushort* W2h = (ushort*)(W + 32 * MB);
  ushort* W2l = (ushort*)(W + 40 * MB);
  float*  X2  = (float*) (W + 48 * MB);   // live steps 5-8
  ushort* Hhi = (ushort*)(W + 64 * MB);   // LN1 out; reused for LN2 out
  ushort* Hlo = (ushort*)(W + 72 * MB);
  float*  Qb  = (float*) (W + 80 * MB);   // QKV fp32, dead after attn
  float*  Kb  = (float*) (W + 96 * MB);
  float*  Vb  = (float*) (W + 112 * MB);
  ushort* F1h = (ushort*)(W + 80 * MB);   // written step 7 (QKV dead)
  ushort* F1l = (ushort*)(W + 112 * MB);
  ushort* Ohi = (ushort*)(W + 128 * MB);  // attn out, dead after Wo GEMM
  ushort* Olo = (ushort*)(W + 136 * MB);

  // 0. weight prep: transpose + split to bf16 hi/lo (N x K)
  wprep_kernel<<<dim3(16, 16), 256, 0, stream>>>(Wq, Wqh, Wql, DIM, DIM);
  wprep_kernel<<<dim3(16, 16), 256, 0, stream>>>(Wk, Wkh, Wkl, DIM, DIM);
  wprep_kernel<<<dim3(16, 16), 256, 0, stream>>>(Wv, Wvh, Wvl, DIM, DIM);
  wprep_kernel<<<dim3(16, 16), 256, 0, stream>>>(Wo, Woh, Wol, DIM, DIM);
  wprep_kernel<<<dim3(64, 16), 256, 0, stream>>>(W1, W1h, W1l, DIM, MLP_DIM);
  wprep_kernel<<<dim3(16, 64), 256, 0, stream>>>(W2, W2h, W2l, MLP_DIM, DIM);
  // 1. h = LN1(x) -> hi/lo
  ln_kernel<<<4096, 256, 0, stream>>>(x, gln1, bln1, Hhi, Hlo);
  // 2. Q,K,V = h @ {Wq,Wk,Wv}  (fp32 out)
  qkv_mfma<<<dim3(8, 32, 3), 256, 0, stream>>>(Hhi, Hlo, Wqh, Wql, Wkh, Wkl,
                                               Wvh, Wvl, Qb, Kb, Vb);
  // 3. o = attention(Q,K,V) -> hi/lo
  attn_kernel<<<dim3(16, 16, 4), 256, 0, stream>>>(Qb, Kb, Vb, Ohi, Olo);
  // 4. x2 = x + o @ Wo   (BM=64, 512 blocks)
  mgemm_kernel<2, 4, 1><<<dim3(8, 64), 256, 0, stream>>>(
      Ohi, Olo, Woh, Wol, nullptr, x, X2, nullptr, nullptr, 4096, DIM, DIM);
  // 5. h2 = LN2(x2) -> hi/lo
  ln_kernel<<<4096, 256, 0, stream>>>(X2, gln2, bln2, Hhi, Hlo);
  // 6. f1 = gelu(h2 @ W1 + b1) -> hi/lo  (128x128, 1024 blocks)
  mgemm_kernel<4, 4, 2><<<dim3(32, 32), 256, 0, stream>>>(
      Hhi, Hlo, W1h, W1l, b1, nullptr, nullptr, F1h, F1l, 4096, MLP_DIM, DIM);
  // 7. out = x2 + f1 @ W2 + b2  (BM=64, 512 blocks)
  mgemm_kernel<2, 4, 3><<<dim3(8, 64), 256, 0, stream>>>(
      F1h, F1l, W2h, W2l, b2, X2, out, nullptr, nullptr, 4096, DIM, MLP_DIM);
}

// Round 9
// 717.611 us; speedup vs baseline: 3.1259x; 1.5199x over previous
//
#include <hip/hip_runtime.h>
#include <math.h>

#define DIM 1024
#define SEQ 1024
#define BATCH 4
#define NHEADS 16
#define HEADD 64
#define MLP_DIM 4096

typedef short short8 __attribute__((ext_vector_type(8)));
typedef float f32x4 __attribute__((ext_vector_type(4)));
#define MFMA(a, b, c) __builtin_amdgcn_mfma_f32_16x16x32_bf16(a, b, c, 0, 0, 0)

__device__ __forceinline__ ushort f2b(float x) {
  unsigned u = __float_as_uint(x);
  unsigned r = (u + 0x7FFFu + ((u >> 16) & 1u)) >> 16;
  return (ushort)r;
}
__device__ __forceinline__ float b2f(ushort h) {
  return __uint_as_float(((unsigned)h) << 16);
}

__device__ __forceinline__ void g2l16(const void* g, void* l) {
  __builtin_amdgcn_global_load_lds((const __attribute__((address_space(1))) void*)g,
                                   (__attribute__((address_space(3))) void*)l, 16, 0, 0);
}

// convert 8 floats (scaled) to bf16 hi + residual lo short8
__device__ __forceinline__ void cvt8(const float* f, float scale, short8& hi, short8& lo) {
#pragma unroll
  for (int i = 0; i < 8; i++) {
    float v = f[i] * scale;
    ushort hv = f2b(v);
    hi[i] = (short)hv;
    lo[i] = (short)f2b(v - b2f(hv));
  }
}

// ---------------- LayerNorm -> bf16 hi/lo ----------------
__global__ __launch_bounds__(256) void ln_kernel(const float* __restrict__ x,
                                                 const float* __restrict__ g,
                                                 const float* __restrict__ b,
                                                 ushort* __restrict__ ohi,
                                                 ushort* __restrict__ olo) {
  int row = blockIdx.x;
  int t = threadIdx.x;
  const float* xr = x + (size_t)row * DIM;
  float4 v = *(const float4*)(xr + t * 4);
  float s  = v.x + v.y + v.z + v.w;
  float sq = v.x * v.x + v.y * v.y + v.z * v.z + v.w * v.w;
#pragma unroll
  for (int off = 32; off > 0; off >>= 1) {
    s  += __shfl_down(s, off);
    sq += __shfl_down(sq, off);
  }
  __shared__ float red_s[4], red_q[4];
  __shared__ float mu_s, inv_s;
  int wid = t >> 6;
  if ((t & 63) == 0) { red_s[wid] = s; red_q[wid] = sq; }
  __syncthreads();
  if (t == 0) {
    float S  = red_s[0] + red_s[1] + red_s[2] + red_s[3];
    float Sq = red_q[0] + red_q[1] + red_q[2] + red_q[3];
    float mu  = S * (1.0f / DIM);
    float var = Sq * (1.0f / DIM) - mu * mu;
    mu_s  = mu;
    inv_s = 1.0f / sqrtf(var + 1e-5f);
  }
  __syncthreads();
  float mu = mu_s, inv = inv_s;
  float4 gv = *(const float4*)(g + t * 4);
  float4 bv = *(const float4*)(b + t * 4);
  float o0 = (v.x - mu) * inv * gv.x + bv.x;
  float o1 = (v.y - mu) * inv * gv.y + bv.y;
  float o2 = (v.z - mu) * inv * gv.z + bv.z;
  float o3 = (v.w - mu) * inv * gv.w + bv.w;
  ushort4 hv, lv;
  hv.x = f2b(o0); lv.x = f2b(o0 - b2f(hv.x));
  hv.y = f2b(o1); lv.y = f2b(o1 - b2f(hv.y));
  hv.z = f2b(o2); lv.z = f2b(o2 - b2f(hv.z));
  hv.w = f2b(o3); lv.w = f2b(o3 - b2f(hv.w));
  *(ushort4*)(ohi + (size_t)row * DIM + t * 4) = hv;
  *(ushort4*)(olo + (size_t)row * DIM + t * 4) = lv;
}

// ---------------- weight prep: transpose KxN fp32 -> NxK bf16 hi/lo --------
__global__ __launch_bounds__(256) void wprep_kernel(const float* __restrict__ W,
                                                    ushort* __restrict__ Whi,
                                                    ushort* __restrict__ Wlo,
                                                    int Kd, int Nd) {
  __shared__ float tile[64][65];
  const int t = threadIdx.x;
  const int n0 = blockIdx.x * 64, k0 = blockIdx.y * 64;
  const int r = t >> 4, c4 = (t & 15) * 4;
#pragma unroll
  for (int i = 0; i < 4; i++) {
    float4 v = *(const float4*)&W[(size_t)(k0 + r + i * 16) * Nd + n0 + c4];
    tile[r + i * 16][c4 + 0] = v.x;
    tile[r + i * 16][c4 + 1] = v.y;
    tile[r + i * 16][c4 + 2] = v.z;
    tile[r + i * 16][c4 + 3] = v.w;
  }
  __syncthreads();
#pragma unroll
  for (int i = 0; i < 4; i++) {
    int nr = r + i * 16;
    float x0 = tile[c4 + 0][nr], x1 = tile[c4 + 1][nr];
    float x2 = tile[c4 + 2][nr], x3 = tile[c4 + 3][nr];
    ushort4 hv, lv;
    hv.x = f2b(x0); lv.x = f2b(x0 - b2f(hv.x));
    hv.y = f2b(x1); lv.y = f2b(x1 - b2f(hv.y));
    hv.z = f2b(x2); lv.z = f2b(x2 - b2f(hv.z));
    hv.w = f2b(x3); lv.w = f2b(x3 - b2f(hv.w));
    *(ushort4*)&Whi[(size_t)(n0 + nr) * Kd + k0 + c4] = hv;
    *(ushort4*)&Wlo[(size_t)(n0 + nr) * Kd + k0 + c4] = lv;
  }
}

// ---------------- split-bf16 MFMA GEMM (validated R4) ----------------
template <int MS, int NS, int EPI>
__device__ __forceinline__ void mgemm_body(
    const ushort* __restrict__ Ahi, const ushort* __restrict__ Alo,
    const ushort* __restrict__ Bhi, const ushort* __restrict__ Blo,
    const float* __restrict__ bias, const float* __restrict__ res,
    float* __restrict__ Cf, ushort* __restrict__ Chi, ushort* __restrict__ Clo,
    int M, int N, int K) {
  constexpr int ASUB = 2 * MS;
  constexpr int BSUB = 2 * NS;
  constexpr int TOT = 2 * (ASUB + BSUB);
  constexpr int PW = TOT / 4;
  __shared__ ushort lds[TOT * 512];

  const int t = threadIdx.x;
  const int l = t & 63;
  const int wid = t >> 6;
  const int wm = wid >> 1, wn = wid & 1;
  const int m0 = blockIdx.y * (ASUB * 16);
  const int n0 = blockIdx.x * (BSUB * 16);
  const int lr = l & 15;
  const int lk = (l >> 4) * 8;

  const ushort* gsrc[PW];
  ushort* ldst[PW];
#pragma unroll
  for (int i = 0; i < PW; i++) {
    int j = wid * PW + i;
    const ushort* base;
    int rowbase, slot;
    if (j < 2 * ASUB) {
      int plane = j & 1, sub = j >> 1;
      base = plane ? Alo : Ahi;
      rowbase = m0 + sub * 16;
      slot = plane * ASUB + sub;
    } else {
      int jb = j - 2 * ASUB;
      int plane = jb & 1, sub = jb >> 1;
      base = plane ? Blo : Bhi;
      rowbase = n0 + sub * 16;
      slot = 2 * ASUB + plane * BSUB + sub;
    }
    gsrc[i] = base + (size_t)(rowbase + lr) * K + lk;
    ldst[i] = &lds[slot * 512];
  }

  f32x4 acc[MS][NS] = {};

  for (int k0 = 0; k0 < K; k0 += 32) {
    __syncthreads();
#pragma unroll
    for (int i = 0; i < PW; i++) {
      g2l16(gsrc[i], ldst[i]);
      gsrc[i] += 32;
    }
    __syncthreads();

    short8 ah[MS], al[MS], bh[NS], bl[NS];
#pragma unroll
    for (int mi = 0; mi < MS; mi++) {
      ah[mi] = *(const short8*)&lds[(wm * MS + mi) * 512 + l * 8];
      al[mi] = *(const short8*)&lds[(ASUB + wm * MS + mi) * 512 + l * 8];
    }
#pragma unroll
    for (int ni = 0; ni < NS; ni++) {
      bh[ni] = *(const short8*)&lds[(2 * ASUB + wn * NS + ni) * 512 + l * 8];
      bl[ni] = *(const short8*)&lds[(2 * ASUB + BSUB + wn * NS + ni) * 512 + l * 8];
    }
#pragma unroll
    for (int mi = 0; mi < MS; mi++)
#pragma unroll
      for (int ni = 0; ni < NS; ni++) {
        acc[mi][ni] = MFMA(ah[mi], bh[ni], acc[mi][ni]);
        acc[mi][ni] = MFMA(ah[mi], bl[ni], acc[mi][ni]);
        acc[mi][ni] = MFMA(al[mi], bh[ni], acc[mi][ni]);
      }
  }

  const int orow0 = m0 + wm * (MS * 16);
  const int ocol0 = n0 + wn * (NS * 16);
#pragma unroll
  for (int mi = 0; mi < MS; mi++) {
#pragma unroll
    for (int r = 0; r < 4; r++) {
      int row = orow0 + mi * 16 + (l >> 4) * 4 + r;
#pragma unroll
      for (int ni = 0; ni < NS; ni++) {
        int col = ocol0 + ni * 16 + lr;
        size_t idx = (size_t)row * N + col;
        float v = acc[mi][ni][r];
        if (EPI == 0) {
          Cf[idx] = v;
        } else if (EPI == 1) {
          Cf[idx] = v + res[idx];
        } else if (EPI == 2) {
          v += bias[col];
          v = 0.5f * v * (1.0f + erff(v * 0.70710678118654752f));
          ushort h = f2b(v);
          Chi[idx] = h;
          Clo[idx] = f2b(v - b2f(h));
        } else {
          Cf[idx] = v + bias[col] + res[idx];
        }
      }
    }
  }
}

template <int MS, int NS, int EPI>
__global__ __launch_bounds__(256, 2) void mgemm_kernel(
    const ushort* __restrict__ Ahi, const ushort* __restrict__ Alo,
    const ushort* __restrict__ Bhi, const ushort* __restrict__ Blo,
    const float* __restrict__ bias, const float* __restrict__ res,
    float* __restrict__ Cf, ushort* __restrict__ Chi, ushort* __restrict__ Clo,
    int M, int N, int K) {
  mgemm_body<MS, NS, EPI>(Ahi, Alo, Bhi, Blo, bias, res, Cf, Chi, Clo, M, N, K);
}

__global__ __launch_bounds__(256, 2) void qkv_mfma(
    const ushort* __restrict__ Ahi, const ushort* __restrict__ Alo,
    const ushort* __restrict__ Wqh, const ushort* __restrict__ Wql,
    const ushort* __restrict__ Wkh, const ushort* __restrict__ Wkl,
    const ushort* __restrict__ Wvh, const ushort* __restrict__ Wvl,
    float* __restrict__ Qo, float* __restrict__ Ko, float* __restrict__ Vo) {
  const ushort* bh = (blockIdx.z == 0) ? Wqh : (blockIdx.z == 1) ? Wkh : Wvh;
  const ushort* bl = (blockIdx.z == 0) ? Wql : (blockIdx.z == 1) ? Wkl : Wvl;
  float* C = (blockIdx.z == 0) ? Qo : (blockIdx.z == 1) ? Ko : Vo;
  mgemm_body<4, 4, 0>(Ahi, Alo, bh, bl, nullptr, nullptr, C, nullptr, nullptr,
                      4096, DIM, DIM);
}

// ---------------- MFMA flash attention ----------------
// Per (bi, n): head matrices are (1024, 64) row-major (faithful .view reinterp).
// Swapped: S^T = K @ Q^T  (A=K natural (kv,d), B=Q natural (q,d); acc col=q).
// Softmax lane-local (16 vals) + shfl_xor 16,32.
// PV as O^T = V^T @ P^T (A=V^T staged transposed, B=P in (q,kv) layout).
// acc_O col=q -> corr rescale, 1/l, and O-write all lane-local.
// Split-bf16 3-pass on both products. Scale 1/8 folded into K conversion.
// Block: 128 q-rows, 4 waves x 32 q; KV tile 64; grid (8,16,4)=512.
#define KSLOT(s, ks, pl) (((s) * 2 + (ks)) * 1024 + (pl) * 512)
#define VSLOT(d, ks, pl) (8192 + ((d) * 2 + (ks)) * 1024 + (pl) * 512)
#define PSLOT(w, qf, ks, pl) (16384 + (w) * 4096 + (((qf) * 2 + (ks)) * 2 + (pl)) * 512)

__global__ __launch_bounds__(256, 2) void attn_mfma(const float* __restrict__ Q,
                                                    const float* __restrict__ K,
                                                    const float* __restrict__ V,
                                                    ushort* __restrict__ Ohi,
                                                    ushort* __restrict__ Olo) {
  __shared__ ushort lds[32768];   // 64 KB: K 16K + V^T 16K + P 4x8K
  const int qt = blockIdx.x;      // 0..7
  const int n  = blockIdx.y;      // 0..15
  const int bi = blockIdx.z;      // 0..3
  const size_t headoff = ((size_t)bi * SEQ + (size_t)n * HEADD) * DIM;
  const float* Qh = Q + headoff;
  const float* Kh = K + headoff;
  const float* Vh = V + headoff;
  const int t = threadIdx.x;
  const int l = t & 63;
  const int w = t >> 6;
  const int lq = l & 15;
  const int h = l >> 4;
  const int qrow = qt * 128 + w * 32;   // wave's first q row

  // Q fragments in registers: [qf][kstep] hi/lo
  short8 qfh[2][2], qfl[2][2];
#pragma unroll
  for (int qf = 0; qf < 2; qf++) {
    const float* qp = Qh + (size_t)(qrow + qf * 16 + lq) * 64 + h * 8;
#pragma unroll
    for (int ks = 0; ks < 2; ks++) {
      float f[8];
      float4 a = *(const float4*)(qp + ks * 32);
      float4 b = *(const float4*)(qp + ks * 32 + 4);
      f[0]=a.x; f[1]=a.y; f[2]=a.z; f[3]=a.w; f[4]=b.x; f[5]=b.y; f[6]=b.z; f[7]=b.w;
      cvt8(f, 1.0f, qfh[qf][ks], qfl[qf][ks]);
    }
  }

  f32x4 accO[4][2] = {};          // [df][qf], col=q lane-local
  float m_run[2] = {-1e30f, -1e30f};
  float l_run[2] = {0.0f, 0.0f};

  for (int tdx = 0; tdx < SEQ / 64; tdx++) {
    const int kvbase = tdx * 64;
    __syncthreads();
    // ---- stage K (wave w -> kv-subtile w), scale 1/8 folded (exact) ----
    {
      const float* kp = Kh + (size_t)(kvbase + 16 * w + lq) * 64 + h * 8;
#pragma unroll
      for (int ks = 0; ks < 2; ks++) {
        float f[8];
        float4 a = *(const float4*)(kp + ks * 32);
        float4 b = *(const float4*)(kp + ks * 32 + 4);
        f[0]=a.x; f[1]=a.y; f[2]=a.z; f[3]=a.w; f[4]=b.x; f[5]=b.y; f[6]=b.z; f[7]=b.w;
        short8 hi, lo;
        cvt8(f, 0.125f, hi, lo);
        *(short8*)&lds[KSLOT(w, ks, 0) + l * 8] = hi;
        *(short8*)&lds[KSLOT(w, ks, 1) + l * 8] = lo;
      }
    }
    // ---- stage V^T (wave w -> d-subtile w) ----
    {
#pragma unroll
      for (int ks = 0; ks < 2; ks++) {
        float f[8];
#pragma unroll
        for (int j = 0; j < 8; j++)
          f[j] = Vh[(size_t)(kvbase + ks * 32 + h * 8 + j) * 64 + 16 * w + lq];
        short8 hi, lo;
        cvt8(f, 1.0f, hi, lo);
        *(short8*)&lds[VSLOT(w, ks, 0) + l * 8] = hi;
        *(short8*)&lds[VSLOT(w, ks, 1) + l * 8] = lo;
      }
    }
    __syncthreads();

    // ---- S^T = K @ Q^T : acc row=kv, col=q (3-pass split) ----
    f32x4 accS[4][2] = {};
#pragma unroll
    for (int ks = 0; ks < 2; ks++) {
      short8 kh[4], kl[4];
#pragma unroll
      for (int s = 0; s < 4; s++) {
        kh[s] = *(const short8*)&lds[KSLOT(s, ks, 0) + l * 8];
        kl[s] = *(const short8*)&lds[KSLOT(s, ks, 1) + l * 8];
      }
#pragma unroll
      for (int s = 0; s < 4; s++)
#pragma unroll
        for (int qf = 0; qf < 2; qf++) {
          accS[s][qf] = MFMA(kh[s], qfh[qf][ks], accS[s][qf]);
          accS[s][qf] = MFMA(kh[s], qfl[qf][ks], accS[s][qf]);
          accS[s][qf] = MFMA(kl[s], qfh[qf][ks], accS[s][qf]);
        }
    }

    // ---- online softmax (per q = lane&15, per qf) ----
    float corr[2];
#pragma unroll
    for (int qf = 0; qf < 2; qf++) {
      float tmax = -1e30f;
#pragma unroll
      for (int s = 0; s < 4; s++)
#pragma unroll
        for (int r = 0; r < 4; r++) tmax = fmaxf(tmax, accS[s][qf][r]);
      tmax = fmaxf(tmax, __shfl_xor(tmax, 16));
      tmax = fmaxf(tmax, __shfl_xor(tmax, 32));
      float mnew = fmaxf(m_run[qf], tmax);
      float c = __expf(m_run[qf] - mnew);
      m_run[qf] = mnew;
      corr[qf] = c;
      float tsum = 0.0f;
#pragma unroll
      for (int s = 0; s < 4; s++)
#pragma unroll
        for (int r = 0; r < 4; r++) {
          float p = __expf(accS[s][qf][r] - mnew);
          accS[s][qf][r] = p;
          tsum += p;
        }
      tsum += __shfl_xor(tsum, 16);
      tsum += __shfl_xor(tsum, 32);
      l_run[qf] = l_run[qf] * c + tsum;
    }

    // ---- pack P -> wave-private LDS in B-fragment order ----
    // value (q=qf*16+lq, kv=s*16+4h+r) -> slot(qf, kv/32),
    // idx = ((kv%32)/8)*128 + lq*8 + (kv%8); r-run contiguous.
#pragma unroll
    for (int qf = 0; qf < 2; qf++)
#pragma unroll
      for (int s = 0; s < 4; s++) {
        f32x4 p = accS[s][qf];
        ushort4 hv, lv;
        hv.x = f2b(p[0]); lv.x = f2b(p[0] - b2f(hv.x));
        hv.y = f2b(p[1]); lv.y = f2b(p[1] - b2f(hv.y));
        hv.z = f2b(p[2]); lv.z = f2b(p[2] - b2f(hv.z));
        hv.w = f2b(p[3]); lv.w = f2b(p[3] - b2f(hv.w));
        int ib = (((s & 1) * 2) + (h >> 1)) * 128 + lq * 8 + (h & 1) * 4;
        *(ushort4*)&lds[PSLOT(w, qf, s >> 1, 0) + ib] = hv;
        *(ushort4*)&lds[PSLOT(w, qf, s >> 1, 1) + ib] = lv;
      }

    // ---- rescale O accumulator (corr lane-local: col=q) ----
#pragma unroll
    for (int df = 0; df < 4; df++)
#pragma unroll
      for (int qf = 0; qf < 2; qf++)
#pragma unroll
        for (int r = 0; r < 4; r++) accO[df][qf][r] *= corr[qf];

    // ---- O^T += V^T @ P^T (3-pass split) ----
#pragma unroll
    for (int ks = 0; ks < 2; ks++) {
      short8 vh[4], vl[4], ph[2], pl[2];
#pragma unroll
      for (int d = 0; d < 4; d++) {
        vh[d] = *(const short8*)&lds[VSLOT(d, ks, 0) + l * 8];
        vl[d] = *(const short8*)&lds[VSLOT(d, ks, 1) + l * 8];
      }
#pragma unroll
      for (int qf = 0; qf < 2; qf++) {
        ph[qf] = *(const short8*)&lds[PSLOT(w, qf, ks, 0) + l * 8];
        pl[qf] = *(const short8*)&lds[PSLOT(w, qf, ks, 1) + l * 8];
      }
#pragma unroll
      for (int d = 0; d < 4; d++)
#pragma unroll
        for (int qf = 0; qf < 2; qf++) {
          accO[d][qf] = MFMA(vh[d], ph[qf], accO[d][qf]);
          accO[d][qf] = MFMA(vl[d], ph[qf], accO[d][qf]);
          accO[d][qf] = MFMA(vh[d], pl[qf], accO[d][qf]);
        }
    }
  }

  // ---- epilogue: normalize + write bf16 hi/lo ----
#pragma unroll
  for (int qf = 0; qf < 2; qf++) {
    float inv = 1.0f / l_run[qf];
    int qg = qrow + qf * 16 + lq;
    size_t base = ((size_t)bi * SEQ + qg) * DIM + n * HEADD;
#pragma unroll
    for (int df = 0; df < 4; df++) {
      f32x4 o = accO[df][qf];
      float v0 = o[0] * inv, v1 = o[1] * inv, v2 = o[2] * inv, v3 = o[3] * inv;
      ushort4 hv, lv;
      hv.x = f2b(v0); lv.x = f2b(v0 - b2f(hv.x));
      hv.y = f2b(v1); lv.y = f2b(v1 - b2f(hv.y));
      hv.z = f2b(v2); lv.z = f2b(v2 - b2f(hv.z));
      hv.w = f2b(v3); lv.w = f2b(v3 - b2f(hv.w));
      size_t a = base + df * 16 + h * 4;
      *(ushort4*)(Ohi + a) = hv;
      *(ushort4*)(Olo + a) = lv;
    }
  }
}

// ---------------- launch ----------------
extern "C" void kernel_launch(void* const* d_in, const int* in_sizes, int n_in,
                              void* d_out, int out_size, void* d_ws, size_t ws_size,
                              hipStream_t stream) {
  const float* x    = (const float*)d_in[0];
  const float* Wq   = (const float*)d_in[1];
  const float* Wk   = (const float*)d_in[2];
  const float* Wv   = (const float*)d_in[3];
  const float* Wo   = (const float*)d_in[4];
  const float* W1   = (const float*)d_in[5];
  const float* b1   = (const float*)d_in[6];
  const float* W2   = (const float*)d_in[7];
  const float* b2   = (const float*)d_in[8];
  const float* gln1 = (const float*)d_in[9];
  const float* bln1 = (const float*)d_in[10];
  const float* gln2 = (const float*)d_in[11];
  const float* bln2 = (const float*)d_in[12];
  float* out = (float*)d_out;
  char* W = (char*)d_ws;

  const size_t MB = 1u << 20;
  ushort* Wqh = (ushort*)(W + 0 * MB);
  ushort* Wql = (ushort*)(W + 2 * MB);
  ushort* Wkh = (ushort*)(W + 4 * MB);
  ushort* Wkl = (ushort*)(W + 6 * MB);
  ushort* Wvh = (ushort*)(W + 8 * MB);
  ushort* Wvl = (ushort*)(W + 10 * MB);
  ushort* Woh = (ushort*)(W + 12 * MB);
  ushort* Wol = (ushort*)(W + 14 * MB);
  ushort* W1h = (ushort*)(W + 16 * MB);
  ushort* W1l = (ushort*)(W + 24 * MB);
  ushort* W2h = (ushort*)(W + 32 * MB);
  ushort* W2l = (ushort*)(W + 40 * MB);
  float*  X2  = (float*) (W + 48 * MB);
  ushort* Hhi = (ushort*)(W + 64 * MB);
  ushort* Hlo = (ushort*)(W + 72 * MB);
  float*  Qb  = (float*) (W + 80 * MB);
  float*  Kb  = (float*) (W + 96 * MB);
  float*  Vb  = (float*) (W + 112 * MB);
  ushort* F1h = (ushort*)(W + 80 * MB);
  ushort* F1l = (ushort*)(W + 112 * MB);
  ushort* Ohi = (ushort*)(W + 128 * MB);
  ushort* Olo = (ushort*)(W + 136 * MB);

  wprep_kernel<<<dim3(16, 16), 256, 0, stream>>>(Wq, Wqh, Wql, DIM, DIM);
  wprep_kernel<<<dim3(16, 16), 256, 0, stream>>>(Wk, Wkh, Wkl, DIM, DIM);
  wprep_kernel<<<dim3(16, 16), 256, 0, stream>>>(Wv, Wvh, Wvl, DIM, DIM);
  wprep_kernel<<<dim3(16, 16), 256, 0, stream>>>(Wo, Woh, Wol, DIM, DIM);
  wprep_kernel<<<dim3(64, 16), 256, 0, stream>>>(W1, W1h, W1l, DIM, MLP_DIM);
  wprep_kernel<<<dim3(16, 64), 256, 0, stream>>>(W2, W2h, W2l, MLP_DIM, DIM);
  ln_kernel<<<4096, 256, 0, stream>>>(x, gln1, bln1, Hhi, Hlo);
  qkv_mfma<<<dim3(8, 32, 3), 256, 0, stream>>>(Hhi, Hlo, Wqh, Wql, Wkh, Wkl,
                                               Wvh, Wvl, Qb, Kb, Vb);
  attn_mfma<<<dim3(8, 16, 4), 256, 0, stream>>>(Qb, Kb, Vb, Ohi, Olo);
  mgemm_kernel<2, 4, 1><<<dim3(8, 64), 256, 0, stream>>>(
      Ohi, Olo, Woh, Wol, nullptr, x, X2, nullptr, nullptr, 4096, DIM, DIM);
  ln_kernel<<<4096, 256, 0, stream>>>(X2, gln2, bln2, Hhi, Hlo);
  mgemm_kernel<4, 4, 2><<<dim3(32, 32), 256, 0, stream>>>(
      Hhi, Hlo, W1h, W1l, b1, nullptr, nullptr, F1h, F1l, 4096, MLP_DIM, DIM);
  mgemm_kernel<2, 4, 3><<<dim3(8, 64), 256, 0, stream>>>(
      F1h, F1l, W2h, W2l, b2, X2, out, nullptr, nullptr, 4096, DIM, MLP_DIM);
}

// Round 11
// 714.999 us; speedup vs baseline: 3.1373x; 1.0037x over previous
//
#include <hip/hip_runtime.h>
#include <math.h>

#define DIM 1024
#define SEQ 1024
#define BATCH 4
#define NHEADS 16
#define HEADD 64
#define MLP_DIM 4096

typedef short short8 __attribute__((ext_vector_type(8)));
typedef float f32x4 __attribute__((ext_vector_type(4)));
#define MFMA(a, b, c) __builtin_amdgcn_mfma_f32_16x16x32_bf16(a, b, c, 0, 0, 0)

__device__ __forceinline__ ushort f2b(float x) {
  unsigned u = __float_as_uint(x);
  unsigned r = (u + 0x7FFFu + ((u >> 16) & 1u)) >> 16;
  return (ushort)r;
}
__device__ __forceinline__ float b2f(ushort h) {
  return __uint_as_float(((unsigned)h) << 16);
}

__device__ __forceinline__ void g2l16(const void* g, void* l) {
  __builtin_amdgcn_global_load_lds((const __attribute__((address_space(1))) void*)g,
                                   (__attribute__((address_space(3))) void*)l, 16, 0, 0);
}

// bijective XCD-aware block swizzle (requires gridDim.x*gridDim.y % 8 == 0).
// Dispatch round-robins linear ids over 8 XCDs; this remap gives XCD k a
// contiguous band of y-tiles so shared A-panels stay in one XCD's L2.
__device__ __forceinline__ void xcd_swz(int& bx, int& by) {
  int gx = gridDim.x;
  int id = blockIdx.x + gx * blockIdx.y;
  int cpx = (gx * gridDim.y) >> 3;
  int sid = (id & 7) * cpx + (id >> 3);
  bx = sid % gx;
  by = sid / gx;
}

// convert 8 floats (scaled) to bf16 hi + residual lo short8
__device__ __forceinline__ void cvt8(const float* f, float scale, short8& hi, short8& lo) {
#pragma unroll
  for (int i = 0; i < 8; i++) {
    float v = f[i] * scale;
    ushort hv = f2b(v);
    hi[i] = (short)hv;
    lo[i] = (short)f2b(v - b2f(hv));
  }
}

// ---------------- LayerNorm -> bf16 hi/lo ----------------
__global__ __launch_bounds__(256) void ln_kernel(const float* __restrict__ x,
                                                 const float* __restrict__ g,
                                                 const float* __restrict__ b,
                                                 ushort* __restrict__ ohi,
                                                 ushort* __restrict__ olo) {
  int row = blockIdx.x;
  int t = threadIdx.x;
  const float* xr = x + (size_t)row * DIM;
  float4 v = *(const float4*)(xr + t * 4);
  float s  = v.x + v.y + v.z + v.w;
  float sq = v.x * v.x + v.y * v.y + v.z * v.z + v.w * v.w;
#pragma unroll
  for (int off = 32; off > 0; off >>= 1) {
    s  += __shfl_down(s, off);
    sq += __shfl_down(sq, off);
  }
  __shared__ float red_s[4], red_q[4];
  __shared__ float mu_s, inv_s;
  int wid = t >> 6;
  if ((t & 63) == 0) { red_s[wid] = s; red_q[wid] = sq; }
  __syncthreads();
  if (t == 0) {
    float S  = red_s[0] + red_s[1] + red_s[2] + red_s[3];
    float Sq = red_q[0] + red_q[1] + red_q[2] + red_q[3];
    float mu  = S * (1.0f / DIM);
    float var = Sq * (1.0f / DIM) - mu * mu;
    mu_s  = mu;
    inv_s = 1.0f / sqrtf(var + 1e-5f);
  }
  __syncthreads();
  float mu = mu_s, inv = inv_s;
  float4 gv = *(const float4*)(g + t * 4);
  float4 bv = *(const float4*)(b + t * 4);
  float o0 = (v.x - mu) * inv * gv.x + bv.x;
  float o1 = (v.y - mu) * inv * gv.y + bv.y;
  float o2 = (v.z - mu) * inv * gv.z + bv.z;
  float o3 = (v.w - mu) * inv * gv.w + bv.w;
  ushort4 hv, lv;
  hv.x = f2b(o0); lv.x = f2b(o0 - b2f(hv.x));
  hv.y = f2b(o1); lv.y = f2b(o1 - b2f(hv.y));
  hv.z = f2b(o2); lv.z = f2b(o2 - b2f(hv.z));
  hv.w = f2b(o3); lv.w = f2b(o3 - b2f(hv.w));
  *(ushort4*)(ohi + (size_t)row * DIM + t * 4) = hv;
  *(ushort4*)(olo + (size_t)row * DIM + t * 4) = lv;
}

// ---------------- weight prep: transpose KxN fp32 -> NxK bf16 hi/lo --------
__global__ __launch_bounds__(256) void wprep_kernel(const float* __restrict__ W,
                                                    ushort* __restrict__ Whi,
                                                    ushort* __restrict__ Wlo,
                                                    int Kd, int Nd) {
  __shared__ float tile[64][65];
  const int t = threadIdx.x;
  const int n0 = blockIdx.x * 64, k0 = blockIdx.y * 64;
  const int r = t >> 4, c4 = (t & 15) * 4;
#pragma unroll
  for (int i = 0; i < 4; i++) {
    float4 v = *(const float4*)&W[(size_t)(k0 + r + i * 16) * Nd + n0 + c4];
    tile[r + i * 16][c4 + 0] = v.x;
    tile[r + i * 16][c4 + 1] = v.y;
    tile[r + i * 16][c4 + 2] = v.z;
    tile[r + i * 16][c4 + 3] = v.w;
  }
  __syncthreads();
#pragma unroll
  for (int i = 0; i < 4; i++) {
    int nr = r + i * 16;
    float x0 = tile[c4 + 0][nr], x1 = tile[c4 + 1][nr];
    float x2 = tile[c4 + 2][nr], x3 = tile[c4 + 3][nr];
    ushort4 hv, lv;
    hv.x = f2b(x0); lv.x = f2b(x0 - b2f(hv.x));
    hv.y = f2b(x1); lv.y = f2b(x1 - b2f(hv.y));
    hv.z = f2b(x2); lv.z = f2b(x2 - b2f(hv.z));
    hv.w = f2b(x3); lv.w = f2b(x3 - b2f(hv.w));
    *(ushort4*)&Whi[(size_t)(n0 + nr) * Kd + k0 + c4] = hv;
    *(ushort4*)&Wlo[(size_t)(n0 + nr) * Kd + k0 + c4] = lv;
  }
}

// ---------------- split-bf16 MFMA GEMM (validated R4; R10: +swz, +occup) ---
template <int MS, int NS, int EPI>
__device__ __forceinline__ void mgemm_body(
    const ushort* __restrict__ Ahi, const ushort* __restrict__ Alo,
    const ushort* __restrict__ Bhi, const ushort* __restrict__ Blo,
    const float* __restrict__ bias, const float* __restrict__ res,
    float* __restrict__ Cf, ushort* __restrict__ Chi, ushort* __restrict__ Clo,
    int M, int N, int K) {
  constexpr int ASUB = 2 * MS;
  constexpr int BSUB = 2 * NS;
  constexpr int TOT = 2 * (ASUB + BSUB);
  constexpr int PW = TOT / 4;
  __shared__ ushort lds[TOT * 512];

  int bx, by;
  xcd_swz(bx, by);
  const int t = threadIdx.x;
  const int l = t & 63;
  const int wid = t >> 6;
  const int wm = wid >> 1, wn = wid & 1;
  const int m0 = by * (ASUB * 16);
  const int n0 = bx * (BSUB * 16);
  const int lr = l & 15;
  const int lk = (l >> 4) * 8;

  const ushort* gsrc[PW];
  ushort* ldst[PW];
#pragma unroll
  for (int i = 0; i < PW; i++) {
    int j = wid * PW + i;
    const ushort* base;
    int rowbase, slot;
    if (j < 2 * ASUB) {
      int plane = j & 1, sub = j >> 1;
      base = plane ? Alo : Ahi;
      rowbase = m0 + sub * 16;
      slot = plane * ASUB + sub;
    } else {
      int jb = j - 2 * ASUB;
      int plane = jb & 1, sub = jb >> 1;
      base = plane ? Blo : Bhi;
      rowbase = n0 + sub * 16;
      slot = 2 * ASUB + plane * BSUB + sub;
    }
    gsrc[i] = base + (size_t)(rowbase + lr) * K + lk;
    ldst[i] = &lds[slot * 512];
  }

  f32x4 acc[MS][NS] = {};

  for (int k0 = 0; k0 < K; k0 += 32) {
    __syncthreads();
#pragma unroll
    for (int i = 0; i < PW; i++) {
      g2l16(gsrc[i], ldst[i]);
      gsrc[i] += 32;
    }
    __syncthreads();

    short8 ah[MS], al[MS], bh[NS], bl[NS];
#pragma unroll
    for (int mi = 0; mi < MS; mi++) {
      ah[mi] = *(const short8*)&lds[(wm * MS + mi) * 512 + l * 8];
      al[mi] = *(const short8*)&lds[(ASUB + wm * MS + mi) * 512 + l * 8];
    }
#pragma unroll
    for (int ni = 0; ni < NS; ni++) {
      bh[ni] = *(const short8*)&lds[(2 * ASUB + wn * NS + ni) * 512 + l * 8];
      bl[ni] = *(const short8*)&lds[(2 * ASUB + BSUB + wn * NS + ni) * 512 + l * 8];
    }
#pragma unroll
    for (int mi = 0; mi < MS; mi++)
#pragma unroll
      for (int ni = 0; ni < NS; ni++) {
        acc[mi][ni] = MFMA(ah[mi], bh[ni], acc[mi][ni]);
        acc[mi][ni] = MFMA(ah[mi], bl[ni], acc[mi][ni]);
        acc[mi][ni] = MFMA(al[mi], bh[ni], acc[mi][ni]);
      }
  }

  const int orow0 = m0 + wm * (MS * 16);
  const int ocol0 = n0 + wn * (NS * 16);
#pragma unroll
  for (int mi = 0; mi < MS; mi++) {
#pragma unroll
    for (int r = 0; r < 4; r++) {
      int row = orow0 + mi * 16 + (l >> 4) * 4 + r;
#pragma unroll
      for (int ni = 0; ni < NS; ni++) {
        int col = ocol0 + ni * 16 + lr;
        size_t idx = (size_t)row * N + col;
        float v = acc[mi][ni][r];
        if (EPI == 0) {
          Cf[idx] = v;
        } else if (EPI == 1) {
          Cf[idx] = v + res[idx];
        } else if (EPI == 2) {
          v += bias[col];
          v = 0.5f * v * (1.0f + erff(v * 0.70710678118654752f));
          ushort h = f2b(v);
          Chi[idx] = h;
          Clo[idx] = f2b(v - b2f(h));
        } else {
          Cf[idx] = v + bias[col] + res[idx];
        }
      }
    }
  }
}

// MINW = min waves/EU: 4 -> 4 blocks/CU for the small-tile GEMMs (48 VGPR,
// 24 KB LDS measured R9 -> fits); 2 for the 128x128 kernels (VGPR unmeasured).
template <int MS, int NS, int EPI, int MINW>
__global__ __launch_bounds__(256, MINW) void mgemm_kernel(
    const ushort* __restrict__ Ahi, const ushort* __restrict__ Alo,
    const ushort* __restrict__ Bhi, const ushort* __restrict__ Blo,
    const float* __restrict__ bias, const float* __restrict__ res,
    float* __restrict__ Cf, ushort* __restrict__ Chi, ushort* __restrict__ Clo,
    int M, int N, int K) {
  mgemm_body<MS, NS, EPI>(Ahi, Alo, Bhi, Blo, bias, res, Cf, Chi, Clo, M, N, K);
}

__global__ __launch_bounds__(256, 2) void qkv_mfma(
    const ushort* __restrict__ Ahi, const ushort* __restrict__ Alo,
    const ushort* __restrict__ Wqh, const ushort* __restrict__ Wql,
    const ushort* __restrict__ Wkh, const ushort* __restrict__ Wkl,
    const ushort* __restrict__ Wvh, const ushort* __restrict__ Wvl,
    float* __restrict__ Qo, float* __restrict__ Ko, float* __restrict__ Vo) {
  const ushort* bh = (blockIdx.z == 0) ? Wqh : (blockIdx.z == 1) ? Wkh : Wvh;
  const ushort* bl = (blockIdx.z == 0) ? Wql : (blockIdx.z == 1) ? Wkl : Wvl;
  float* C = (blockIdx.z == 0) ? Qo : (blockIdx.z == 1) ? Ko : Vo;
  mgemm_body<4, 4, 0>(Ahi, Alo, bh, bl, nullptr, nullptr, C, nullptr, nullptr,
                      4096, DIM, DIM);
}

// ---------------- MFMA flash attention (validated R9) ----------------
#define KSLOT(s, ks, pl) (((s) * 2 + (ks)) * 1024 + (pl) * 512)
#define VSLOT(d, ks, pl) (8192 + ((d) * 2 + (ks)) * 1024 + (pl) * 512)
#define PSLOT(w, qf, ks, pl) (16384 + (w) * 4096 + (((qf) * 2 + (ks)) * 2 + (pl)) * 512)

__global__ __launch_bounds__(256, 2) void attn_mfma(const float* __restrict__ Q,
                                                    const float* __restrict__ K,
                                                    const float* __restrict__ V,
                                                    ushort* __restrict__ Ohi,
                                                    ushort* __restrict__ Olo) {
  __shared__ ushort lds[32768];   // 64 KB: K 16K + V^T 16K + P 4x8K
  const int qt = blockIdx.x;      // 0..7
  const int n  = blockIdx.y;      // 0..15
  const int bi = blockIdx.z;      // 0..3
  const size_t headoff = ((size_t)bi * SEQ + (size_t)n * HEADD) * DIM;
  const float* Qh = Q + headoff;
  const float* Kh = K + headoff;
  const float* Vh = V + headoff;
  const int t = threadIdx.x;
  const int l = t & 63;
  const int w = t >> 6;
  const int lq = l & 15;
  const int h = l >> 4;
  const int qrow = qt * 128 + w * 32;   // wave's first q row

  // Q fragments in registers: [qf][kstep] hi/lo
  short8 qfh[2][2], qfl[2][2];
#pragma unroll
  for (int qf = 0; qf < 2; qf++) {
    const float* qp = Qh + (size_t)(qrow + qf * 16 + lq) * 64 + h * 8;
#pragma unroll
    for (int ks = 0; ks < 2; ks++) {
      float f[8];
      float4 a = *(const float4*)(qp + ks * 32);
      float4 b = *(const float4*)(qp + ks * 32 + 4);
      f[0]=a.x; f[1]=a.y; f[2]=a.z; f[3]=a.w; f[4]=b.x; f[5]=b.y; f[6]=b.z; f[7]=b.w;
      cvt8(f, 1.0f, qfh[qf][ks], qfl[qf][ks]);
    }
  }

  f32x4 accO[4][2] = {};          // [df][qf], col=q lane-local
  float m_run[2] = {-1e30f, -1e30f};
  float l_run[2] = {0.0f, 0.0f};

  for (int tdx = 0; tdx < SEQ / 64; tdx++) {
    const int kvbase = tdx * 64;
    __syncthreads();
    // ---- stage K (wave w -> kv-subtile w), scale 1/8 folded (exact) ----
    {
      const float* kp = Kh + (size_t)(kvbase + 16 * w + lq) * 64 + h * 8;
#pragma unroll
      for (int ks = 0; ks < 2; ks++) {
        float f[8];
        float4 a = *(const float4*)(kp + ks * 32);
        float4 b = *(const float4*)(kp + ks * 32 + 4);
        f[0]=a.x; f[1]=a.y; f[2]=a.z; f[3]=a.w; f[4]=b.x; f[5]=b.y; f[6]=b.z; f[7]=b.w;
        short8 hi, lo;
        cvt8(f, 0.125f, hi, lo);
        *(short8*)&lds[KSLOT(w, ks, 0) + l * 8] = hi;
        *(short8*)&lds[KSLOT(w, ks, 1) + l * 8] = lo;
      }
    }
    // ---- stage V^T (wave w -> d-subtile w) ----
    {
#pragma unroll
      for (int ks = 0; ks < 2; ks++) {
        float f[8];
#pragma unroll
        for (int j = 0; j < 8; j++)
          f[j] = Vh[(size_t)(kvbase + ks * 32 + h * 8 + j) * 64 + 16 * w + lq];
        short8 hi, lo;
        cvt8(f, 1.0f, hi, lo);
        *(short8*)&lds[VSLOT(w, ks, 0) + l * 8] = hi;
        *(short8*)&lds[VSLOT(w, ks, 1) + l * 8] = lo;
      }
    }
    __syncthreads();

    // ---- S^T = K @ Q^T : acc row=kv, col=q (3-pass split) ----
    f32x4 accS[4][2] = {};
#pragma unroll
    for (int ks = 0; ks < 2; ks++) {
      short8 kh[4], kl[4];
#pragma unroll
      for (int s = 0; s < 4; s++) {
        kh[s] = *(const short8*)&lds[KSLOT(s, ks, 0) + l * 8];
        kl[s] = *(const short8*)&lds[KSLOT(s, ks, 1) + l * 8];
      }
#pragma unroll
      for (int s = 0; s < 4; s++)
#pragma unroll
        for (int qf = 0; qf < 2; qf++) {
          accS[s][qf] = MFMA(kh[s], qfh[qf][ks], accS[s][qf]);
          accS[s][qf] = MFMA(kh[s], qfl[qf][ks], accS[s][qf]);
          accS[s][qf] = MFMA(kl[s], qfh[qf][ks], accS[s][qf]);
        }
    }

    // ---- online softmax (per q = lane&15, per qf) ----
    float corr[2];
#pragma unroll
    for (int qf = 0; qf < 2; qf++) {
      float tmax = -1e30f;
#pragma unroll
      for (int s = 0; s < 4; s++)
#pragma unroll
        for (int r = 0; r < 4; r++) tmax = fmaxf(tmax, accS[s][qf][r]);
      tmax = fmaxf(tmax, __shfl_xor(tmax, 16));
      tmax = fmaxf(tmax, __shfl_xor(tmax, 32));
      float mnew = fmaxf(m_run[qf], tmax);
      float c = __expf(m_run[qf] - mnew);
      m_run[qf] = mnew;
      corr[qf] = c;
      float tsum = 0.0f;
#pragma unroll
      for (int s = 0; s < 4; s++)
#pragma unroll
        for (int r = 0; r < 4; r++) {
          float p = __expf(accS[s][qf][r] - mnew);
          accS[s][qf][r] = p;
          tsum += p;
        }
      tsum += __shfl_xor(tsum, 16);
      tsum += __shfl_xor(tsum, 32);
      l_run[qf] = l_run[qf] * c + tsum;
    }

    // ---- pack P -> wave-private LDS in B-fragment order ----
#pragma unroll
    for (int qf = 0; qf < 2; qf++)
#pragma unroll
      for (int s = 0; s < 4; s++) {
        f32x4 p = accS[s][qf];
        ushort4 hv, lv;
        hv.x = f2b(p[0]); lv.x = f2b(p[0] - b2f(hv.x));
        hv.y = f2b(p[1]); lv.y = f2b(p[1] - b2f(hv.y));
        hv.z = f2b(p[2]); lv.z = f2b(p[2] - b2f(hv.z));
        hv.w = f2b(p[3]); lv.w = f2b(p[3] - b2f(hv.w));
        int ib = (((s & 1) * 2) + (h >> 1)) * 128 + lq * 8 + (h & 1) * 4;
        *(ushort4*)&lds[PSLOT(w, qf, s >> 1, 0) + ib] = hv;
        *(ushort4*)&lds[PSLOT(w, qf, s >> 1, 1) + ib] = lv;
      }

    // ---- rescale O accumulator (corr lane-local: col=q) ----
#pragma unroll
    for (int df = 0; df < 4; df++)
#pragma unroll
      for (int qf = 0; qf < 2; qf++)
#pragma unroll
        for (int r = 0; r < 4; r++) accO[df][qf][r] *= corr[qf];

    // ---- O^T += V^T @ P^T (3-pass split) ----
#pragma unroll
    for (int ks = 0; ks < 2; ks++) {
      short8 vh[4], vl[4], ph[2], pl[2];
#pragma unroll
      for (int d = 0; d < 4; d++) {
        vh[d] = *(const short8*)&lds[VSLOT(d, ks, 0) + l * 8];
        vl[d] = *(const short8*)&lds[VSLOT(d, ks, 1) + l * 8];
      }
#pragma unroll
      for (int qf = 0; qf < 2; qf++) {
        ph[qf] = *(const short8*)&lds[PSLOT(w, qf, ks, 0) + l * 8];
        pl[qf] = *(const short8*)&lds[PSLOT(w, qf, ks, 1) + l * 8];
      }
#pragma unroll
      for (int d = 0; d < 4; d++)
#pragma unroll
        for (int qf = 0; qf < 2; qf++) {
          accO[d][qf] = MFMA(vh[d], ph[qf], accO[d][qf]);
          accO[d][qf] = MFMA(vl[d], ph[qf], accO[d][qf]);
          accO[d][qf] = MFMA(vh[d], pl[qf], accO[d][qf]);
        }
    }
  }

  // ---- epilogue: normalize + write bf16 hi/lo ----
#pragma unroll
  for (int qf = 0; qf < 2; qf++) {
    float inv = 1.0f / l_run[qf];
    int qg = qrow + qf * 16 + lq;
    size_t base = ((size_t)bi * SEQ + qg) * DIM + n * HEADD;
#pragma unroll
    for (int df = 0; df < 4; df++) {
      f32x4 o = accO[df][qf];
      float v0 = o[0] * inv, v1 = o[1] * inv, v2 = o[2] * inv, v3 = o[3] * inv;
      ushort4 hv, lv;
      hv.x = f2b(v0); lv.x = f2b(v0 - b2f(hv.x));
      hv.y = f2b(v1); lv.y = f2b(v1 - b2f(hv.y));
      hv.z = f2b(v2); lv.z = f2b(v2 - b2f(hv.z));
      hv.w = f2b(v3); lv.w = f2b(v3 - b2f(hv.w));
      size_t a = base + df * 16 + h * 4;
      *(ushort4*)(Ohi + a) = hv;
      *(ushort4*)(Olo + a) = lv;
    }
  }
}

// ---------------- launch ----------------
extern "C" void kernel_launch(void* const* d_in, const int* in_sizes, int n_in,
                              void* d_out, int out_size, void* d_ws, size_t ws_size,
                              hipStream_t stream) {
  const float* x    = (const float*)d_in[0];
  const float* Wq   = (const float*)d_in[1];
  const float* Wk   = (const float*)d_in[2];
  const float* Wv   = (const float*)d_in[3];
  const float* Wo   = (const float*)d_in[4];
  const float* W1   = (const float*)d_in[5];
  const float* b1   = (const float*)d_in[6];
  const float* W2   = (const float*)d_in[7];
  const float* b2   = (const float*)d_in[8];
  const float* gln1 = (const float*)d_in[9];
  const float* bln1 = (const float*)d_in[10];
  const float* gln2 = (const float*)d_in[11];
  const float* bln2 = (const float*)d_in[12];
  float* out = (float*)d_out;
  char* W = (char*)d_ws;

  const size_t MB = 1u << 20;
  ushort* Wqh = (ushort*)(W + 0 * MB);
  ushort* Wql = (ushort*)(W + 2 * MB);
  ushort* Wkh = (ushort*)(W + 4 * MB);
  ushort* Wkl = (ushort*)(W + 6 * MB);
  ushort* Wvh = (ushort*)(W + 8 * MB);
  ushort* Wvl = (ushort*)(W + 10 * MB);
  ushort* Woh = (ushort*)(W + 12 * MB);
  ushort* Wol = (ushort*)(W + 14 * MB);
  ushort* W1h = (ushort*)(W + 16 * MB);
  ushort* W1l = (ushort*)(W + 24 * MB);
  ushort* W2h = (ushort*)(W + 32 * MB);
  ushort* W2l = (ushort*)(W + 40 * MB);
  float*  X2  = (float*) (W + 48 * MB);
  ushort* Hhi = (ushort*)(W + 64 * MB);
  ushort* Hlo = (ushort*)(W + 72 * MB);
  float*  Qb  = (float*) (W + 80 * MB);
  float*  Kb  = (float*) (W + 96 * MB);
  float*  Vb  = (float*) (W + 112 * MB);
  ushort* F1h = (ushort*)(W + 80 * MB);
  ushort* F1l = (ushort*)(W + 112 * MB);
  ushort* Ohi = (ushort*)(W + 128 * MB);
  ushort* Olo = (ushort*)(W + 136 * MB);

  wprep_kernel<<<dim3(16, 16), 256, 0, stream>>>(Wq, Wqh, Wql, DIM, DIM);
  wprep_kernel<<<dim3(16, 16), 256, 0, stream>>>(Wk, Wkh, Wkl, DIM, DIM);
  wprep_kernel<<<dim3(16, 16), 256, 0, stream>>>(Wv, Wvh, Wvl, DIM, DIM);
  wprep_kernel<<<dim3(16, 16), 256, 0, stream>>>(Wo, Woh, Wol, DIM, DIM);
  wprep_kernel<<<dim3(64, 16), 256, 0, stream>>>(W1, W1h, W1l, DIM, MLP_DIM);
  wprep_kernel<<<dim3(16, 64), 256, 0, stream>>>(W2, W2h, W2l, MLP_DIM, DIM);
  ln_kernel<<<4096, 256, 0, stream>>>(x, gln1, bln1, Hhi, Hlo);
  qkv_mfma<<<dim3(8, 32, 3), 256, 0, stream>>>(Hhi, Hlo, Wqh, Wql, Wkh, Wkl,
                                               Wvh, Wvl, Qb, Kb, Vb);
  attn_mfma<<<dim3(8, 16, 4), 256, 0, stream>>>(Qb, Kb, Vb, Ohi, Olo);
  mgemm_kernel<2, 4, 1, 4><<<dim3(8, 64), 256, 0, stream>>>(
      Ohi, Olo, Woh, Wol, nullptr, x, X2, nullptr, nullptr, 4096, DIM, DIM);
  ln_kernel<<<4096, 256, 0, stream>>>(X2, gln2, bln2, Hhi, Hlo);
  mgemm_kernel<4, 4, 2, 2><<<dim3(32, 32), 256, 0, stream>>>(
      Hhi, Hlo, W1h, W1l, b1, nullptr, nullptr, F1h, F1l, 4096, MLP_DIM, DIM);
  mgemm_kernel<2, 4, 3, 4><<<dim3(8, 64), 256, 0, stream>>>(
      F1h, F1l, W2h, W2l, b2, X2, out, nullptr, nullptr, 4096, DIM, MLP_DIM);
}